// Round 1
// 480.598 us; speedup vs baseline: 1.1692x; 1.1692x over previous
//
#include <hip/hip_runtime.h>
#include <math.h>

// ---------------------------------------------------------------------------
// GCN-VAE fused pipeline for MI355X.
// R7: algebraic collapse. The model is fully affine (no activations), so
// consecutive GCN layers fold:   mean = A^2 X (We@Wm) + r*(be@Wm) + bm,
// out = A^2 z (Wd1@Wd2) + r*(bd1@Wd2) + bd2, with r = A*1 (rank-1 bias).
// head_kernel and both decoder matmuls disappear; both decoder aggs run on
// 64-col z-space (128 B/row gathers instead of 256 B/row). CSR build,
// agg loop shape and matmul tile are the verified R6 versions.
// ---------------------------------------------------------------------------

__device__ inline float bf2f_lo(unsigned int v) {
    return __uint_as_float(v << 16);
}
__device__ inline float bf2f_hi(unsigned int v) {
    return __uint_as_float(v & 0xFFFF0000u);
}
__device__ inline float bf2f(unsigned short u) {
    return __uint_as_float(((unsigned int)u) << 16);
}
__device__ inline unsigned short f2bf(float f) {
    unsigned int u = __float_as_uint(f);
    return (unsigned short)((u + 0x7FFFu + ((u >> 16) & 1u)) >> 16);
}
__device__ inline unsigned int get_xcd() {
    unsigned int x;
    asm volatile("s_getreg_b32 %0, hwreg(HW_REG_XCC_ID)" : "=s"(x));
    return x & 7u;
}

__global__ void zero_kernel(int* __restrict__ p, int n) {
    int i = blockIdx.x * blockDim.x + threadIdx.x;
    if (i < n) p[i] = 0;
}

// Pass 1: bucket edges (+self-loops) by dst>>8 into per-(bucket,XCD) slices.
__global__ __launch_bounds__(256) void bucketize_kernel(
    const int* __restrict__ src, const int* __restrict__ dst, int E, int N,
    int capS, uint2* __restrict__ pairs, int* __restrict__ gcnt) {
    __shared__ int lcnt[256];
    __shared__ int lbase[256];
    int tid = threadIdx.x;
    int total = E + N;
    int base = blockIdx.x * 4096;
    unsigned int x = get_xcd();
    lcnt[tid] = 0;
    __syncthreads();
    int d[16], s[16], rk[16];
#pragma unroll
    for (int j = 0; j < 16; j++) {
        int idx = base + j * 256 + tid;
        d[j] = -1;
        if (idx < total) {
            if (idx < E) { d[j] = dst[idx]; s[j] = src[idx]; }
            else         { d[j] = idx - E; s[j] = d[j]; }
            rk[j] = atomicAdd(&lcnt[d[j] >> 8], 1);
        }
    }
    __syncthreads();
    if (lcnt[tid] > 0) lbase[tid] = atomicAdd(&gcnt[tid * 8 + (int)x],
                                              lcnt[tid]);
    __syncthreads();
#pragma unroll
    for (int j = 0; j < 16; j++) {
        if (d[j] >= 0) {
            int b = d[j] >> 8;
            int pos = lbase[b] + rk[j];
            if (pos < capS)
                pairs[(size_t)(b * 8 + (int)x) * capS + pos] =
                    make_uint2((unsigned)d[j], (unsigned)s[j]);
        }
    }
}

// Pass 2: scan bucket totals -> bucket bases; offs[N] = grand total.
__global__ __launch_bounds__(256) void scan_bases_kernel(
    const int* __restrict__ gcnt, int nb, int capS, int* __restrict__ bbase,
    int* __restrict__ offs, int N) {
    __shared__ int lds[256];
    int tid = threadIdx.x;
    int t = 0;
    if (tid < nb) {
#pragma unroll
        for (int x = 0; x < 8; x++) {
            int v = gcnt[tid * 8 + x];
            if (v > capS) v = capS;
            t += v;
        }
    }
    lds[tid] = t;
    __syncthreads();
    for (int off = 1; off < 256; off <<= 1) {
        int u = (tid >= off) ? lds[tid - off] : 0;
        __syncthreads();
        lds[tid] += u;
        __syncthreads();
    }
    bbase[tid] = lds[tid] - t;
    if (tid == 255) offs[N] = lds[255];
}

// Pass 3: one block per bucket; LDS counting sort by dst&255; coalesced out.
__global__ __launch_bounds__(256) void build_kernel(
    const uint2* __restrict__ pairs, const int* __restrict__ gcnt, int capS,
    const int* __restrict__ bbase, int N, int* __restrict__ offs,
    float* __restrict__ dinv, int* __restrict__ esrc) {
    __shared__ int cnt[256];
    __shared__ int loff[256];
    __shared__ int cur[256];
    __shared__ int S[10240];
    int b = blockIdx.x;
    int tid = threadIdx.x;
    cnt[tid] = 0;
    __syncthreads();
    int szx[8];
#pragma unroll
    for (int x = 0; x < 8; x++) {
        int v = gcnt[b * 8 + x];
        if (v > capS) v = capS;
        szx[x] = v;
    }
#pragma unroll
    for (int x = 0; x < 8; x++) {
        const uint2* bp = pairs + (size_t)(b * 8 + x) * capS;
        for (int i = tid; i < szx[x]; i += 256)
            atomicAdd(&cnt[bp[i].x & 255u], 1);
    }
    __syncthreads();
    int c = cnt[tid];
    loff[tid] = c;
    __syncthreads();
    for (int off = 1; off < 256; off <<= 1) {
        int u = (tid >= off) ? loff[tid - off] : 0;
        __syncthreads();
        loff[tid] += u;
        __syncthreads();
    }
    int excl = loff[tid] - c;
    cur[tid] = excl;
    int total = loff[255];
    int base = bbase[b];
    int d0 = b << 8;
    if (d0 + tid < N) {
        offs[d0 + tid] = base + excl;
        dinv[d0 + tid] = rsqrtf((float)c);   // c >= 1 (self-loop)
    }
    __syncthreads();
#pragma unroll
    for (int x = 0; x < 8; x++) {
        const uint2* bp = pairs + (size_t)(b * 8 + x) * capS;
        for (int i = tid; i < szx[x]; i += 256) {
            uint2 p = bp[i];
            int pos = atomicAdd(&cur[p.x & 255u], 1);
            if (pos < 10240) S[pos] = (int)p.y;
        }
    }
    __syncthreads();
    if (total > 10240) total = 10240;
    for (int j = tid; j < total; j += 256) esrc[base + j] = S[j];
}

// Collapse weights on-device (tiny):
//  Wc[k][2j]=sum_m We[k][m]*Wm[m][j], Wc[k][2j+1]=sum_m We[k][m]*Wl[m][j]
//  Wd[k][c]=sum_m Wd1[k][m]*Wd2[m][c]
//  bc[2j]=be@Wm, bc[2j+1]=be@Wl; b2c = interleave(bm,bl); bd12 = bd1@Wd2
__global__ __launch_bounds__(256) void wcomb_kernel(
    const float* __restrict__ We, const float* __restrict__ be,
    const float* __restrict__ Wm, const float* __restrict__ bm,
    const float* __restrict__ Wl, const float* __restrict__ bl,
    const float* __restrict__ Wd1, const float* __restrict__ bd1,
    const float* __restrict__ Wd2, float* __restrict__ Wc,
    float* __restrict__ bc, float* __restrict__ b2c, float* __restrict__ Wd,
    float* __restrict__ bd12) {
    int i = blockIdx.x * 256 + threadIdx.x;
    if (i < 16384) {                          // Wc (128x128 interleaved)
        int k = i >> 7, c = i & 127, j = c >> 1;
        const float* Wx = (c & 1) ? Wl : Wm;
        float s = 0.f;
        for (int m = 0; m < 128; m++) s += We[k * 128 + m] * Wx[m * 64 + j];
        Wc[k * 128 + c] = s;
    } else if (i < 16384 + 8192) {            // Wd (64x128)
        int t = i - 16384;
        int k = t >> 7, c = t & 127;
        float s = 0.f;
        for (int m = 0; m < 128; m++) s += Wd1[k * 128 + m] * Wd2[m * 128 + c];
        Wd[k * 128 + c] = s;
    } else if (i < 16384 + 8192 + 128) {      // bc
        int c = i - (16384 + 8192), j = c >> 1;
        const float* Wx = (c & 1) ? Wl : Wm;
        float s = 0.f;
        for (int m = 0; m < 128; m++) s += be[m] * Wx[m * 64 + j];
        bc[c] = s;
    } else if (i < 16384 + 8192 + 256) {      // b2c
        int c = i - (16384 + 8192 + 128);
        b2c[c] = (c & 1) ? bl[c >> 1] : bm[c >> 1];
    } else if (i < 16384 + 8192 + 384) {      // bd12
        int c = i - (16384 + 8192 + 256);
        float s = 0.f;
        for (int m = 0; m < 128; m++) s += bd1[m] * Wd2[m * 128 + c];
        bd12[c] = s;
    }
}

// Tiled matmul: out[N,128] = X[N,K] @ W[K,128], bf16 out, dinv row prescale.
template <int K, bool XBF, bool SCALE>
__global__ __launch_bounds__(256) void matmul_kernel(
    const void* __restrict__ Xv, const float* __restrict__ W,
    const float* __restrict__ dinv, unsigned short* __restrict__ out, int N) {
    const int M = 128;
    __shared__ float ldsW[K][64];
    __shared__ float ldsX[64][K];
    int tid = threadIdx.x;
    int row0 = blockIdx.x * 64;
    int col0 = blockIdx.y * 64;

    for (int i = tid; i < K * 16; i += 256) {
        int k = i >> 4, j4 = i & 15;
        ((float4*)&ldsW[k][0])[j4] =
            *(const float4*)&W[(size_t)k * M + col0 + j4 * 4];
    }
    int maxr = N - row0; if (maxr > 64) maxr = 64;
    if (XBF) {
        const unsigned short* X = (const unsigned short*)Xv;
        for (int i = tid; i < maxr * (K / 8); i += 256) {
            int r = i / (K / 8), c8 = i % (K / 8);
            uint4 u = *(const uint4*)&X[(size_t)(row0 + r) * K + c8 * 8];
            float* dp = &ldsX[r][c8 * 8];
            dp[0] = bf2f_lo(u.x); dp[1] = bf2f_hi(u.x);
            dp[2] = bf2f_lo(u.y); dp[3] = bf2f_hi(u.y);
            dp[4] = bf2f_lo(u.z); dp[5] = bf2f_hi(u.z);
            dp[6] = bf2f_lo(u.w); dp[7] = bf2f_hi(u.w);
        }
    } else {
        const float* X = (const float*)Xv;
        for (int i = tid; i < maxr * (K / 4); i += 256) {
            int r = i / (K / 4), k4 = i % (K / 4);
            ((float4*)&ldsX[r][0])[k4] =
                *(const float4*)&X[(size_t)(row0 + r) * K + k4 * 4];
        }
    }
    __syncthreads();

    int cg = tid & 15, rg = tid >> 4;
    int rbase = rg * 4, cbase = cg * 4;
    float acc[4][4] = {};
    for (int k = 0; k < K; k += 4) {
        float4 xv[4];
#pragma unroll
        for (int r = 0; r < 4; r++)
            xv[r] = *(const float4*)&ldsX[rbase + r][k];
        const float* xp = (const float*)xv;
#pragma unroll
        for (int kk = 0; kk < 4; kk++) {
            float4 wv = *(const float4*)&ldsW[k + kk][cbase];
#pragma unroll
            for (int r = 0; r < 4; r++) {
                float xs = xp[r * 4 + kk];
                acc[r][0] += xs * wv.x;
                acc[r][1] += xs * wv.y;
                acc[r][2] += xs * wv.z;
                acc[r][3] += xs * wv.w;
            }
        }
    }
#pragma unroll
    for (int r = 0; r < 4; r++) {
        int row = row0 + rbase + r;
        if (row < N) {
            float sc = SCALE ? dinv[row] : 1.0f;
            ushort4 o;
            o.x = f2bf(acc[r][0] * sc); o.y = f2bf(acc[r][1] * sc);
            o.z = f2bf(acc[r][2] * sc); o.w = f2bf(acc[r][3] * sc);
            *(ushort4*)&out[(size_t)row * M + col0 + cbase] = o;
        }
    }
}

// Final matmul: out[N,128] = Q[N,64]@Wd + r[row]*b1[col] + b2[col], fp32 out.
__global__ __launch_bounds__(256) void matmul_out_kernel(
    const unsigned short* __restrict__ X, const float* __restrict__ W,
    const float* __restrict__ rvec, const float* __restrict__ b1,
    const float* __restrict__ b2, float* __restrict__ out, int N) {
    const int K = 64, M = 128;
    __shared__ float ldsW[K][64];
    __shared__ float ldsX[64][K];
    int tid = threadIdx.x;
    int row0 = blockIdx.x * 64;
    int col0 = blockIdx.y * 64;

    for (int i = tid; i < K * 16; i += 256) {
        int k = i >> 4, j4 = i & 15;
        ((float4*)&ldsW[k][0])[j4] =
            *(const float4*)&W[(size_t)k * M + col0 + j4 * 4];
    }
    int maxr = N - row0; if (maxr > 64) maxr = 64;
    for (int i = tid; i < maxr * (K / 8); i += 256) {
        int r = i / (K / 8), c8 = i % (K / 8);
        uint4 u = *(const uint4*)&X[(size_t)(row0 + r) * K + c8 * 8];
        float* dp = &ldsX[r][c8 * 8];
        dp[0] = bf2f_lo(u.x); dp[1] = bf2f_hi(u.x);
        dp[2] = bf2f_lo(u.y); dp[3] = bf2f_hi(u.y);
        dp[4] = bf2f_lo(u.z); dp[5] = bf2f_hi(u.z);
        dp[6] = bf2f_lo(u.w); dp[7] = bf2f_hi(u.w);
    }
    __syncthreads();

    int cg = tid & 15, rg = tid >> 4;
    int rbase = rg * 4, cbase = cg * 4;
    float acc[4][4] = {};
    for (int k = 0; k < K; k += 4) {
        float4 xv[4];
#pragma unroll
        for (int r = 0; r < 4; r++)
            xv[r] = *(const float4*)&ldsX[rbase + r][k];
        const float* xp = (const float*)xv;
#pragma unroll
        for (int kk = 0; kk < 4; kk++) {
            float4 wv = *(const float4*)&ldsW[k + kk][cbase];
#pragma unroll
            for (int r = 0; r < 4; r++) {
                float xs = xp[r * 4 + kk];
                acc[r][0] += xs * wv.x;
                acc[r][1] += xs * wv.y;
                acc[r][2] += xs * wv.z;
                acc[r][3] += xs * wv.w;
            }
        }
    }
    float4 b1v = *(const float4*)&b1[col0 + cbase];
    float4 b2v = *(const float4*)&b2[col0 + cbase];
#pragma unroll
    for (int r = 0; r < 4; r++) {
        int row = row0 + rbase + r;
        if (row < N) {
            float rr = rvec[row];
            float4 o = make_float4(acc[r][0] + rr * b1v.x + b2v.x,
                                   acc[r][1] + rr * b1v.y + b2v.y,
                                   acc[r][2] + rr * b1v.z + b2v.z,
                                   acc[r][3] + rr * b1v.w + b2v.w);
            *(float4*)&out[(size_t)row * M + col0 + cbase] = o;
        }
    }
}

// 128-col aggregation over dinv-prescaled bf16 rows (verified R2 loop shape).
// One wave per dst; lane owns cols {2*lane, 2*lane+1}.  WR: also emit
// r[d] = dinv[d]*sum(dinv[src]) (rank-1 bias vector, = A*ones).
template <bool PRE, bool WR>
__global__ __launch_bounds__(256) void agg_kernel(
    const unsigned short* __restrict__ Y, const int* __restrict__ offsets,
    const int* __restrict__ esrc, const float* __restrict__ dinv,
    unsigned short* __restrict__ out, float* __restrict__ rout, int N) {
    int wid = (blockIdx.x * blockDim.x + threadIdx.x) >> 6;
    int lane = threadIdx.x & 63;
    if (wid >= N) return;
    int beg = offsets[wid], end = offsets[wid + 1];
    const unsigned int* Yu = (const unsigned int*)Y;  // ushort2 pairs
    float ax = 0.f, ay = 0.f, ad = 0.f;
    int e = beg;
    for (; e + 4 <= end; e += 4) {
        int s0 = esrc[e], s1 = esrc[e + 1], s2 = esrc[e + 2], s3 = esrc[e + 3];
        unsigned int v0 = Yu[(size_t)s0 * 64 + lane];
        unsigned int v1 = Yu[(size_t)s1 * 64 + lane];
        unsigned int v2 = Yu[(size_t)s2 * 64 + lane];
        unsigned int v3 = Yu[(size_t)s3 * 64 + lane];
        if (WR) ad += dinv[s0] + dinv[s1] + dinv[s2] + dinv[s3];
        ax += bf2f_lo(v0) + bf2f_lo(v1) + bf2f_lo(v2) + bf2f_lo(v3);
        ay += bf2f_hi(v0) + bf2f_hi(v1) + bf2f_hi(v2) + bf2f_hi(v3);
    }
    for (; e < end; e++) {
        int s0 = esrc[e];
        unsigned int v0 = Yu[(size_t)s0 * 64 + lane];
        if (WR) ad += dinv[s0];
        ax += bf2f_lo(v0);
        ay += bf2f_hi(v0);
    }
    float dd = dinv[wid];
    float rx = ax * dd, ry = ay * dd;
    if (PRE) { rx *= dd; ry *= dd; }
    unsigned int packed = (unsigned int)f2bf(rx) |
                          ((unsigned int)f2bf(ry) << 16);
    ((unsigned int*)out)[(size_t)wid * 64 + lane] = packed;
    if (WR && lane == 0) rout[wid] = ad * dd;
}

// Second encoder agg + fused VAE head epilogue.  Input V = dinv*(A X Wc)
// with Wc columns interleaved (even=mean-path, odd=lv-path); lane j holds
// (T_mean[j], T_lv[j]).  mean = T + r*bc + b2c; z = noise*exp(.5 lv)+mean;
// zb = dinv*z (bf16, prescaled for the decoder aggregation chain).
__global__ __launch_bounds__(256) void aggmeanlv_kernel(
    const unsigned short* __restrict__ Y, const int* __restrict__ offsets,
    const int* __restrict__ esrc, const float* __restrict__ dinv,
    const float* __restrict__ rvec, const float* __restrict__ bc,
    const float* __restrict__ b2c, const float* __restrict__ noise,
    float* __restrict__ mean, float* __restrict__ lv, float* __restrict__ z,
    unsigned short* __restrict__ zb, int N) {
    int wid = (blockIdx.x * blockDim.x + threadIdx.x) >> 6;
    int lane = threadIdx.x & 63;
    if (wid >= N) return;
    int beg = offsets[wid], end = offsets[wid + 1];
    const unsigned int* Yu = (const unsigned int*)Y;
    float ax = 0.f, ay = 0.f;
    int e = beg;
    for (; e + 4 <= end; e += 4) {
        int s0 = esrc[e], s1 = esrc[e + 1], s2 = esrc[e + 2], s3 = esrc[e + 3];
        unsigned int v0 = Yu[(size_t)s0 * 64 + lane];
        unsigned int v1 = Yu[(size_t)s1 * 64 + lane];
        unsigned int v2 = Yu[(size_t)s2 * 64 + lane];
        unsigned int v3 = Yu[(size_t)s3 * 64 + lane];
        ax += bf2f_lo(v0) + bf2f_lo(v1) + bf2f_lo(v2) + bf2f_lo(v3);
        ay += bf2f_hi(v0) + bf2f_hi(v1) + bf2f_hi(v2) + bf2f_hi(v3);
    }
    for (; e < end; e++) {
        unsigned int v0 = Yu[(size_t)esrc[e] * 64 + lane];
        ax += bf2f_lo(v0);
        ay += bf2f_hi(v0);
    }
    float dd = dinv[wid];
    float rr = rvec[wid];
    float2 bcv = ((const float2*)bc)[lane];
    float2 b2v = ((const float2*)b2c)[lane];
    float m = ax * dd + rr * bcv.x + b2v.x;
    float l = ay * dd + rr * bcv.y + b2v.y;
    float nv = noise[(size_t)wid * 64 + lane];
    float zv = nv * expf(0.5f * l) + m;
    size_t o = (size_t)wid * 64 + lane;
    mean[o] = m;
    lv[o] = l;
    z[o] = zv;
    zb[o] = f2bf(zv * dd);
}

// 64-col aggregation (decoder, z-space): lane owns one bf16 column; each
// edge gathers one 128 B row (half the bytes of the 128-col agg).
template <bool PRE>
__global__ __launch_bounds__(256) void agg64_kernel(
    const unsigned short* __restrict__ Y, const int* __restrict__ offsets,
    const int* __restrict__ esrc, const float* __restrict__ dinv,
    unsigned short* __restrict__ out, int N) {
    int wid = (blockIdx.x * blockDim.x + threadIdx.x) >> 6;
    int lane = threadIdx.x & 63;
    if (wid >= N) return;
    int beg = offsets[wid], end = offsets[wid + 1];
    float ax = 0.f;
    int e = beg;
    for (; e + 4 <= end; e += 4) {
        int s0 = esrc[e], s1 = esrc[e + 1], s2 = esrc[e + 2], s3 = esrc[e + 3];
        unsigned short v0 = Y[(size_t)s0 * 64 + lane];
        unsigned short v1 = Y[(size_t)s1 * 64 + lane];
        unsigned short v2 = Y[(size_t)s2 * 64 + lane];
        unsigned short v3 = Y[(size_t)s3 * 64 + lane];
        ax += bf2f(v0) + bf2f(v1) + bf2f(v2) + bf2f(v3);
    }
    for (; e < end; e++) {
        ax += bf2f(Y[(size_t)esrc[e] * 64 + lane]);
    }
    float dd = dinv[wid];
    float rx = ax * dd;
    if (PRE) rx *= dd;
    out[(size_t)wid * 64 + lane] = f2bf(rx);
}

extern "C" void kernel_launch(void* const* d_in, const int* in_sizes, int n_in,
                              void* d_out, int out_size, void* d_ws,
                              size_t ws_size, hipStream_t stream) {
    const float* feature = (const float*)d_in[0];
    const int*   ei      = (const int*)d_in[1];
    const float* noise   = (const float*)d_in[2];
    const float* W_enc   = (const float*)d_in[3];
    const float* b_enc   = (const float*)d_in[4];
    const float* W_mean  = (const float*)d_in[5];
    const float* b_mean  = (const float*)d_in[6];
    const float* W_lv    = (const float*)d_in[7];
    const float* b_lv    = (const float*)d_in[8];
    const float* W_d1    = (const float*)d_in[9];
    const float* b_d1    = (const float*)d_in[10];
    const float* W_d2    = (const float*)d_in[11];
    const float* b_d2    = (const float*)d_in[12];

    int N = in_sizes[0] / 128;
    int E = in_sizes[1] / 2;
    int nb = (N + 255) >> 8;

    float* z_out    = (float*)d_out;
    float* mean_out = z_out + (size_t)N * 64;
    float* lv_out   = z_out + (size_t)N * 128;
    float* gout     = z_out + (size_t)N * 192;

    char* ws = (char*)d_ws;
    unsigned short* Ybf = (unsigned short*)ws; ws += (size_t)N * 128 * 2;
    unsigned short* Hbf = (unsigned short*)ws; ws += (size_t)N * 128 * 2;
    unsigned short* Zbf = (unsigned short*)ws; ws += (size_t)N * 64 * 2;
    int*   esrc  = (int*)ws;   ws += (size_t)(E + N) * 4;
    int*   offs  = (int*)ws;   ws += (size_t)(N + 1) * 4;
    float* dinv  = (float*)ws; ws += (size_t)N * 4;
    int*   gcnt  = (int*)ws;   ws += 256 * 8 * 4;
    int*   bbase = (int*)ws;   ws += 256 * 4;
    float* rvec  = (float*)ws; ws += (size_t)N * 4;
    float* Wc    = (float*)ws; ws += 128 * 128 * 4;
    float* Wd    = (float*)ws; ws += 64 * 128 * 4;
    float* bc    = (float*)ws; ws += 128 * 4;
    float* b2c   = (float*)ws; ws += 128 * 4;
    float* bd12  = (float*)ws; ws += 128 * 4;

    // `pairs` ALIASES Ybf+Hbf (CSR build completes before matmuls touch Ybf).
    uint2* pairs = (uint2*)Ybf;
    size_t pairRegion = (size_t)N * 128 * 2 * 2;
    int capS = 1536;
    int capMax = (int)(pairRegion / (256 * 8 * sizeof(uint2)));
    if (capS > capMax) capS = capMax;

    const int* src = ei;
    const int* dst = ei + E;
    int total = E + N;

    // ---- CSR build (coalesced counting sort) ----
    zero_kernel<<<(256 * 8 + 255) / 256, 256, 0, stream>>>(gcnt, 256 * 8);
    bucketize_kernel<<<(total + 4095) / 4096, 256, 0, stream>>>(
        src, dst, E, N, capS, pairs, gcnt);
    scan_bases_kernel<<<1, 256, 0, stream>>>(gcnt, nb, capS, bbase, offs, N);
    build_kernel<<<nb, 256, 0, stream>>>(pairs, gcnt, capS, bbase, N, offs,
                                         dinv, esrc);

    // ---- collapsed weights (tiny) ----
    wcomb_kernel<<<(16384 + 8192 + 384 + 255) / 256, 256, 0, stream>>>(
        W_enc, b_enc, W_mean, b_mean, W_lv, b_lv, W_d1, b_d1, W_d2,
        Wc, bc, b2c, Wd, bd12);

    int gx = (N + 63) / 64;
    int aggBlocks = (int)(((size_t)N * 64 + 255) / 256);

    // ---- encoder: meanlv = A^2 X Wc + r*bc + b2c ----
    matmul_kernel<128, false, true><<<dim3(gx, 2), 256, 0, stream>>>(
        feature, Wc, dinv, Ybf, N);                      // U = dinv*(X@Wc)
    agg_kernel<true, true><<<aggBlocks, 256, 0, stream>>>(
        Ybf, offs, esrc, dinv, Hbf, rvec, N);            // V = dinv*(A X Wc), r
    aggmeanlv_kernel<<<aggBlocks, 256, 0, stream>>>(
        Hbf, offs, esrc, dinv, rvec, bc, b2c, noise,
        mean_out, lv_out, z_out, Zbf, N);                // mean/lv/z + zb

    // ---- decoder: out = A^2 z Wd + r*bd12 + bd2 ----
    agg64_kernel<true><<<aggBlocks, 256, 0, stream>>>(
        Zbf, offs, esrc, dinv, Ybf, N);                  // P = dinv*(A z)
    agg64_kernel<false><<<aggBlocks, 256, 0, stream>>>(
        Ybf, offs, esrc, dinv, Hbf, N);                  // Q = A^2 z
    matmul_out_kernel<<<dim3(gx, 2), 256, 0, stream>>>(
        Hbf, Wd, rvec, bd12, b_d2, gout, N);             // out (fp32)
}

// Round 2
// 453.374 us; speedup vs baseline: 1.2394x; 1.0600x over previous
//
#include <hip/hip_runtime.h>
#include <math.h>

// ---------------------------------------------------------------------------
// GCN-VAE fused pipeline for MI355X.
// R8: matmul occupancy fix. R7's rocprof showed matmul_out_kernel at 72us
// with VGPR=244 / Occupancy=9.5% / VALUBusy=20% -- the compiler fully
// unrolled the K-loop and register-pipelined every LDS load. Fix:
// __launch_bounds__(256,4) (VGPR<=128 -> 4 waves/SIMD), #pragma unroll 2
// on K-loops, and +4-float LDS row padding (kills the 4-way same-bank
// conflict on the per-wave ldsX row reads). Everything else (CSR build,
// agg kernels, algebraic collapse) is the verified R7 version, numerics
// untouched.
// ---------------------------------------------------------------------------

__device__ inline float bf2f_lo(unsigned int v) {
    return __uint_as_float(v << 16);
}
__device__ inline float bf2f_hi(unsigned int v) {
    return __uint_as_float(v & 0xFFFF0000u);
}
__device__ inline float bf2f(unsigned short u) {
    return __uint_as_float(((unsigned int)u) << 16);
}
__device__ inline unsigned short f2bf(float f) {
    unsigned int u = __float_as_uint(f);
    return (unsigned short)((u + 0x7FFFu + ((u >> 16) & 1u)) >> 16);
}
__device__ inline unsigned int get_xcd() {
    unsigned int x;
    asm volatile("s_getreg_b32 %0, hwreg(HW_REG_XCC_ID)" : "=s"(x));
    return x & 7u;
}

__global__ void zero_kernel(int* __restrict__ p, int n) {
    int i = blockIdx.x * blockDim.x + threadIdx.x;
    if (i < n) p[i] = 0;
}

// Pass 1: bucket edges (+self-loops) by dst>>8 into per-(bucket,XCD) slices.
__global__ __launch_bounds__(256) void bucketize_kernel(
    const int* __restrict__ src, const int* __restrict__ dst, int E, int N,
    int capS, uint2* __restrict__ pairs, int* __restrict__ gcnt) {
    __shared__ int lcnt[256];
    __shared__ int lbase[256];
    int tid = threadIdx.x;
    int total = E + N;
    int base = blockIdx.x * 4096;
    unsigned int x = get_xcd();
    lcnt[tid] = 0;
    __syncthreads();
    int d[16], s[16], rk[16];
#pragma unroll
    for (int j = 0; j < 16; j++) {
        int idx = base + j * 256 + tid;
        d[j] = -1;
        if (idx < total) {
            if (idx < E) { d[j] = dst[idx]; s[j] = src[idx]; }
            else         { d[j] = idx - E; s[j] = d[j]; }
            rk[j] = atomicAdd(&lcnt[d[j] >> 8], 1);
        }
    }
    __syncthreads();
    if (lcnt[tid] > 0) lbase[tid] = atomicAdd(&gcnt[tid * 8 + (int)x],
                                              lcnt[tid]);
    __syncthreads();
#pragma unroll
    for (int j = 0; j < 16; j++) {
        if (d[j] >= 0) {
            int b = d[j] >> 8;
            int pos = lbase[b] + rk[j];
            if (pos < capS)
                pairs[(size_t)(b * 8 + (int)x) * capS + pos] =
                    make_uint2((unsigned)d[j], (unsigned)s[j]);
        }
    }
}

// Pass 2: scan bucket totals -> bucket bases; offs[N] = grand total.
__global__ __launch_bounds__(256) void scan_bases_kernel(
    const int* __restrict__ gcnt, int nb, int capS, int* __restrict__ bbase,
    int* __restrict__ offs, int N) {
    __shared__ int lds[256];
    int tid = threadIdx.x;
    int t = 0;
    if (tid < nb) {
#pragma unroll
        for (int x = 0; x < 8; x++) {
            int v = gcnt[tid * 8 + x];
            if (v > capS) v = capS;
            t += v;
        }
    }
    lds[tid] = t;
    __syncthreads();
    for (int off = 1; off < 256; off <<= 1) {
        int u = (tid >= off) ? lds[tid - off] : 0;
        __syncthreads();
        lds[tid] += u;
        __syncthreads();
    }
    bbase[tid] = lds[tid] - t;
    if (tid == 255) offs[N] = lds[255];
}

// Pass 3: one block per bucket; LDS counting sort by dst&255; coalesced out.
__global__ __launch_bounds__(256) void build_kernel(
    const uint2* __restrict__ pairs, const int* __restrict__ gcnt, int capS,
    const int* __restrict__ bbase, int N, int* __restrict__ offs,
    float* __restrict__ dinv, int* __restrict__ esrc) {
    __shared__ int cnt[256];
    __shared__ int loff[256];
    __shared__ int cur[256];
    __shared__ int S[10240];
    int b = blockIdx.x;
    int tid = threadIdx.x;
    cnt[tid] = 0;
    __syncthreads();
    int szx[8];
#pragma unroll
    for (int x = 0; x < 8; x++) {
        int v = gcnt[b * 8 + x];
        if (v > capS) v = capS;
        szx[x] = v;
    }
#pragma unroll
    for (int x = 0; x < 8; x++) {
        const uint2* bp = pairs + (size_t)(b * 8 + x) * capS;
        for (int i = tid; i < szx[x]; i += 256)
            atomicAdd(&cnt[bp[i].x & 255u], 1);
    }
    __syncthreads();
    int c = cnt[tid];
    loff[tid] = c;
    __syncthreads();
    for (int off = 1; off < 256; off <<= 1) {
        int u = (tid >= off) ? loff[tid - off] : 0;
        __syncthreads();
        loff[tid] += u;
        __syncthreads();
    }
    int excl = loff[tid] - c;
    cur[tid] = excl;
    int total = loff[255];
    int base = bbase[b];
    int d0 = b << 8;
    if (d0 + tid < N) {
        offs[d0 + tid] = base + excl;
        dinv[d0 + tid] = rsqrtf((float)c);   // c >= 1 (self-loop)
    }
    __syncthreads();
#pragma unroll
    for (int x = 0; x < 8; x++) {
        const uint2* bp = pairs + (size_t)(b * 8 + x) * capS;
        for (int i = tid; i < szx[x]; i += 256) {
            uint2 p = bp[i];
            int pos = atomicAdd(&cur[p.x & 255u], 1);
            if (pos < 10240) S[pos] = (int)p.y;
        }
    }
    __syncthreads();
    if (total > 10240) total = 10240;
    for (int j = tid; j < total; j += 256) esrc[base + j] = S[j];
}

// Collapse weights on-device (tiny):
//  Wc[k][2j]=sum_m We[k][m]*Wm[m][j], Wc[k][2j+1]=sum_m We[k][m]*Wl[m][j]
//  Wd[k][c]=sum_m Wd1[k][m]*Wd2[m][c]
//  bc[2j]=be@Wm, bc[2j+1]=be@Wl; b2c = interleave(bm,bl); bd12 = bd1@Wd2
__global__ __launch_bounds__(256) void wcomb_kernel(
    const float* __restrict__ We, const float* __restrict__ be,
    const float* __restrict__ Wm, const float* __restrict__ bm,
    const float* __restrict__ Wl, const float* __restrict__ bl,
    const float* __restrict__ Wd1, const float* __restrict__ bd1,
    const float* __restrict__ Wd2, float* __restrict__ Wc,
    float* __restrict__ bc, float* __restrict__ b2c, float* __restrict__ Wd,
    float* __restrict__ bd12) {
    int i = blockIdx.x * 256 + threadIdx.x;
    if (i < 16384) {                          // Wc (128x128 interleaved)
        int k = i >> 7, c = i & 127, j = c >> 1;
        const float* Wx = (c & 1) ? Wl : Wm;
        float s = 0.f;
        for (int m = 0; m < 128; m++) s += We[k * 128 + m] * Wx[m * 64 + j];
        Wc[k * 128 + c] = s;
    } else if (i < 16384 + 8192) {            // Wd (64x128)
        int t = i - 16384;
        int k = t >> 7, c = t & 127;
        float s = 0.f;
        for (int m = 0; m < 128; m++) s += Wd1[k * 128 + m] * Wd2[m * 128 + c];
        Wd[k * 128 + c] = s;
    } else if (i < 16384 + 8192 + 128) {      // bc
        int c = i - (16384 + 8192), j = c >> 1;
        const float* Wx = (c & 1) ? Wl : Wm;
        float s = 0.f;
        for (int m = 0; m < 128; m++) s += be[m] * Wx[m * 64 + j];
        bc[c] = s;
    } else if (i < 16384 + 8192 + 256) {      // b2c
        int c = i - (16384 + 8192 + 128);
        b2c[c] = (c & 1) ? bl[c >> 1] : bm[c >> 1];
    } else if (i < 16384 + 8192 + 384) {      // bd12
        int c = i - (16384 + 8192 + 256);
        float s = 0.f;
        for (int m = 0; m < 128; m++) s += bd1[m] * Wd2[m * 128 + c];
        bd12[c] = s;
    }
}

// Tiled matmul: out[N,128] = X[N,K] @ W[K,128], bf16 out, dinv row prescale.
// launch_bounds(256,4): cap VGPR at 128 so the scheduler keeps >=4 w/SIMD.
// ldsX padded +4 floats: per-wave row reads land 2-way (free) not 4-way.
template <int K, bool XBF, bool SCALE>
__global__ __launch_bounds__(256, 4) void matmul_kernel(
    const void* __restrict__ Xv, const float* __restrict__ W,
    const float* __restrict__ dinv, unsigned short* __restrict__ out, int N) {
    const int M = 128;
    const int KP = K + 4;
    __shared__ float ldsW[K][64];
    __shared__ float ldsX[64][KP];
    int tid = threadIdx.x;
    int row0 = blockIdx.x * 64;
    int col0 = blockIdx.y * 64;

    for (int i = tid; i < K * 16; i += 256) {
        int k = i >> 4, j4 = i & 15;
        ((float4*)&ldsW[k][0])[j4] =
            *(const float4*)&W[(size_t)k * M + col0 + j4 * 4];
    }
    int maxr = N - row0; if (maxr > 64) maxr = 64;
    if (XBF) {
        const unsigned short* X = (const unsigned short*)Xv;
        for (int i = tid; i < maxr * (K / 8); i += 256) {
            int r = i / (K / 8), c8 = i % (K / 8);
            uint4 u = *(const uint4*)&X[(size_t)(row0 + r) * K + c8 * 8];
            float* dp = &ldsX[r][c8 * 8];
            dp[0] = bf2f_lo(u.x); dp[1] = bf2f_hi(u.x);
            dp[2] = bf2f_lo(u.y); dp[3] = bf2f_hi(u.y);
            dp[4] = bf2f_lo(u.z); dp[5] = bf2f_hi(u.z);
            dp[6] = bf2f_lo(u.w); dp[7] = bf2f_hi(u.w);
        }
    } else {
        const float* X = (const float*)Xv;
        for (int i = tid; i < maxr * (K / 4); i += 256) {
            int r = i / (K / 4), k4 = i % (K / 4);
            *(float4*)&ldsX[r][k4 * 4] =
                *(const float4*)&X[(size_t)(row0 + r) * K + k4 * 4];
        }
    }
    __syncthreads();

    int cg = tid & 15, rg = tid >> 4;
    int rbase = rg * 4, cbase = cg * 4;
    float acc[4][4] = {};
#pragma unroll 2
    for (int k = 0; k < K; k += 4) {
        float4 xv[4];
#pragma unroll
        for (int r = 0; r < 4; r++)
            xv[r] = *(const float4*)&ldsX[rbase + r][k];
        const float* xp = (const float*)xv;
#pragma unroll
        for (int kk = 0; kk < 4; kk++) {
            float4 wv = *(const float4*)&ldsW[k + kk][cbase];
#pragma unroll
            for (int r = 0; r < 4; r++) {
                float xs = xp[r * 4 + kk];
                acc[r][0] += xs * wv.x;
                acc[r][1] += xs * wv.y;
                acc[r][2] += xs * wv.z;
                acc[r][3] += xs * wv.w;
            }
        }
    }
#pragma unroll
    for (int r = 0; r < 4; r++) {
        int row = row0 + rbase + r;
        if (row < N) {
            float sc = SCALE ? dinv[row] : 1.0f;
            ushort4 o;
            o.x = f2bf(acc[r][0] * sc); o.y = f2bf(acc[r][1] * sc);
            o.z = f2bf(acc[r][2] * sc); o.w = f2bf(acc[r][3] * sc);
            *(ushort4*)&out[(size_t)row * M + col0 + cbase] = o;
        }
    }
}

// Final matmul: out[N,128] = Q[N,64]@Wd + r[row]*b1[col] + b2[col], fp32 out.
__global__ __launch_bounds__(256, 4) void matmul_out_kernel(
    const unsigned short* __restrict__ X, const float* __restrict__ W,
    const float* __restrict__ rvec, const float* __restrict__ b1,
    const float* __restrict__ b2, float* __restrict__ out, int N) {
    const int K = 64, M = 128;
    const int KP = K + 4;
    __shared__ float ldsW[K][64];
    __shared__ float ldsX[64][KP];
    int tid = threadIdx.x;
    int row0 = blockIdx.x * 64;
    int col0 = blockIdx.y * 64;

    for (int i = tid; i < K * 16; i += 256) {
        int k = i >> 4, j4 = i & 15;
        ((float4*)&ldsW[k][0])[j4] =
            *(const float4*)&W[(size_t)k * M + col0 + j4 * 4];
    }
    int maxr = N - row0; if (maxr > 64) maxr = 64;
    for (int i = tid; i < maxr * (K / 8); i += 256) {
        int r = i / (K / 8), c8 = i % (K / 8);
        uint4 u = *(const uint4*)&X[(size_t)(row0 + r) * K + c8 * 8];
        float* dp = &ldsX[r][c8 * 8];
        dp[0] = bf2f_lo(u.x); dp[1] = bf2f_hi(u.x);
        dp[2] = bf2f_lo(u.y); dp[3] = bf2f_hi(u.y);
        dp[4] = bf2f_lo(u.z); dp[5] = bf2f_hi(u.z);
        dp[6] = bf2f_lo(u.w); dp[7] = bf2f_hi(u.w);
    }
    __syncthreads();

    int cg = tid & 15, rg = tid >> 4;
    int rbase = rg * 4, cbase = cg * 4;
    float acc[4][4] = {};
#pragma unroll 2
    for (int k = 0; k < K; k += 4) {
        float4 xv[4];
#pragma unroll
        for (int r = 0; r < 4; r++)
            xv[r] = *(const float4*)&ldsX[rbase + r][k];
        const float* xp = (const float*)xv;
#pragma unroll
        for (int kk = 0; kk < 4; kk++) {
            float4 wv = *(const float4*)&ldsW[k + kk][cbase];
#pragma unroll
            for (int r = 0; r < 4; r++) {
                float xs = xp[r * 4 + kk];
                acc[r][0] += xs * wv.x;
                acc[r][1] += xs * wv.y;
                acc[r][2] += xs * wv.z;
                acc[r][3] += xs * wv.w;
            }
        }
    }
    float4 b1v = *(const float4*)&b1[col0 + cbase];
    float4 b2v = *(const float4*)&b2[col0 + cbase];
#pragma unroll
    for (int r = 0; r < 4; r++) {
        int row = row0 + rbase + r;
        if (row < N) {
            float rr = rvec[row];
            float4 o = make_float4(acc[r][0] + rr * b1v.x + b2v.x,
                                   acc[r][1] + rr * b1v.y + b2v.y,
                                   acc[r][2] + rr * b1v.z + b2v.z,
                                   acc[r][3] + rr * b1v.w + b2v.w);
            *(float4*)&out[(size_t)row * M + col0 + cbase] = o;
        }
    }
}

// 128-col aggregation over dinv-prescaled bf16 rows (verified R2 loop shape).
// One wave per dst; lane owns cols {2*lane, 2*lane+1}.  WR: also emit
// r[d] = dinv[d]*sum(dinv[src]) (rank-1 bias vector, = A*ones).
template <bool PRE, bool WR>
__global__ __launch_bounds__(256) void agg_kernel(
    const unsigned short* __restrict__ Y, const int* __restrict__ offsets,
    const int* __restrict__ esrc, const float* __restrict__ dinv,
    unsigned short* __restrict__ out, float* __restrict__ rout, int N) {
    int wid = (blockIdx.x * blockDim.x + threadIdx.x) >> 6;
    int lane = threadIdx.x & 63;
    if (wid >= N) return;
    int beg = offsets[wid], end = offsets[wid + 1];
    const unsigned int* Yu = (const unsigned int*)Y;  // ushort2 pairs
    float ax = 0.f, ay = 0.f, ad = 0.f;
    int e = beg;
    for (; e + 4 <= end; e += 4) {
        int s0 = esrc[e], s1 = esrc[e + 1], s2 = esrc[e + 2], s3 = esrc[e + 3];
        unsigned int v0 = Yu[(size_t)s0 * 64 + lane];
        unsigned int v1 = Yu[(size_t)s1 * 64 + lane];
        unsigned int v2 = Yu[(size_t)s2 * 64 + lane];
        unsigned int v3 = Yu[(size_t)s3 * 64 + lane];
        if (WR) ad += dinv[s0] + dinv[s1] + dinv[s2] + dinv[s3];
        ax += bf2f_lo(v0) + bf2f_lo(v1) + bf2f_lo(v2) + bf2f_lo(v3);
        ay += bf2f_hi(v0) + bf2f_hi(v1) + bf2f_hi(v2) + bf2f_hi(v3);
    }
    for (; e < end; e++) {
        int s0 = esrc[e];
        unsigned int v0 = Yu[(size_t)s0 * 64 + lane];
        if (WR) ad += dinv[s0];
        ax += bf2f_lo(v0);
        ay += bf2f_hi(v0);
    }
    float dd = dinv[wid];
    float rx = ax * dd, ry = ay * dd;
    if (PRE) { rx *= dd; ry *= dd; }
    unsigned int packed = (unsigned int)f2bf(rx) |
                          ((unsigned int)f2bf(ry) << 16);
    ((unsigned int*)out)[(size_t)wid * 64 + lane] = packed;
    if (WR && lane == 0) rout[wid] = ad * dd;
}

// Second encoder agg + fused VAE head epilogue.  Input V = dinv*(A X Wc)
// with Wc columns interleaved (even=mean-path, odd=lv-path); lane j holds
// (T_mean[j], T_lv[j]).  mean = T + r*bc + b2c; z = noise*exp(.5 lv)+mean;
// zb = dinv*z (bf16, prescaled for the decoder aggregation chain).
__global__ __launch_bounds__(256) void aggmeanlv_kernel(
    const unsigned short* __restrict__ Y, const int* __restrict__ offsets,
    const int* __restrict__ esrc, const float* __restrict__ dinv,
    const float* __restrict__ rvec, const float* __restrict__ bc,
    const float* __restrict__ b2c, const float* __restrict__ noise,
    float* __restrict__ mean, float* __restrict__ lv, float* __restrict__ z,
    unsigned short* __restrict__ zb, int N) {
    int wid = (blockIdx.x * blockDim.x + threadIdx.x) >> 6;
    int lane = threadIdx.x & 63;
    if (wid >= N) return;
    int beg = offsets[wid], end = offsets[wid + 1];
    const unsigned int* Yu = (const unsigned int*)Y;
    float ax = 0.f, ay = 0.f;
    int e = beg;
    for (; e + 4 <= end; e += 4) {
        int s0 = esrc[e], s1 = esrc[e + 1], s2 = esrc[e + 2], s3 = esrc[e + 3];
        unsigned int v0 = Yu[(size_t)s0 * 64 + lane];
        unsigned int v1 = Yu[(size_t)s1 * 64 + lane];
        unsigned int v2 = Yu[(size_t)s2 * 64 + lane];
        unsigned int v3 = Yu[(size_t)s3 * 64 + lane];
        ax += bf2f_lo(v0) + bf2f_lo(v1) + bf2f_lo(v2) + bf2f_lo(v3);
        ay += bf2f_hi(v0) + bf2f_hi(v1) + bf2f_hi(v2) + bf2f_hi(v3);
    }
    for (; e < end; e++) {
        unsigned int v0 = Yu[(size_t)esrc[e] * 64 + lane];
        ax += bf2f_lo(v0);
        ay += bf2f_hi(v0);
    }
    float dd = dinv[wid];
    float rr = rvec[wid];
    float2 bcv = ((const float2*)bc)[lane];
    float2 b2v = ((const float2*)b2c)[lane];
    float m = ax * dd + rr * bcv.x + b2v.x;
    float l = ay * dd + rr * bcv.y + b2v.y;
    float nv = noise[(size_t)wid * 64 + lane];
    float zv = nv * expf(0.5f * l) + m;
    size_t o = (size_t)wid * 64 + lane;
    mean[o] = m;
    lv[o] = l;
    z[o] = zv;
    zb[o] = f2bf(zv * dd);
}

// 64-col aggregation (decoder, z-space): lane owns one bf16 column; each
// edge gathers one 128 B row (half the bytes of the 128-col agg).
template <bool PRE>
__global__ __launch_bounds__(256) void agg64_kernel(
    const unsigned short* __restrict__ Y, const int* __restrict__ offsets,
    const int* __restrict__ esrc, const float* __restrict__ dinv,
    unsigned short* __restrict__ out, int N) {
    int wid = (blockIdx.x * blockDim.x + threadIdx.x) >> 6;
    int lane = threadIdx.x & 63;
    if (wid >= N) return;
    int beg = offsets[wid], end = offsets[wid + 1];
    float ax = 0.f;
    int e = beg;
    for (; e + 4 <= end; e += 4) {
        int s0 = esrc[e], s1 = esrc[e + 1], s2 = esrc[e + 2], s3 = esrc[e + 3];
        unsigned short v0 = Y[(size_t)s0 * 64 + lane];
        unsigned short v1 = Y[(size_t)s1 * 64 + lane];
        unsigned short v2 = Y[(size_t)s2 * 64 + lane];
        unsigned short v3 = Y[(size_t)s3 * 64 + lane];
        ax += bf2f(v0) + bf2f(v1) + bf2f(v2) + bf2f(v3);
    }
    for (; e < end; e++) {
        ax += bf2f(Y[(size_t)esrc[e] * 64 + lane]);
    }
    float dd = dinv[wid];
    float rx = ax * dd;
    if (PRE) rx *= dd;
    out[(size_t)wid * 64 + lane] = f2bf(rx);
}

extern "C" void kernel_launch(void* const* d_in, const int* in_sizes, int n_in,
                              void* d_out, int out_size, void* d_ws,
                              size_t ws_size, hipStream_t stream) {
    const float* feature = (const float*)d_in[0];
    const int*   ei      = (const int*)d_in[1];
    const float* noise   = (const float*)d_in[2];
    const float* W_enc   = (const float*)d_in[3];
    const float* b_enc   = (const float*)d_in[4];
    const float* W_mean  = (const float*)d_in[5];
    const float* b_mean  = (const float*)d_in[6];
    const float* W_lv    = (const float*)d_in[7];
    const float* b_lv    = (const float*)d_in[8];
    const float* W_d1    = (const float*)d_in[9];
    const float* b_d1    = (const float*)d_in[10];
    const float* W_d2    = (const float*)d_in[11];
    const float* b_d2    = (const float*)d_in[12];

    int N = in_sizes[0] / 128;
    int E = in_sizes[1] / 2;
    int nb = (N + 255) >> 8;

    float* z_out    = (float*)d_out;
    float* mean_out = z_out + (size_t)N * 64;
    float* lv_out   = z_out + (size_t)N * 128;
    float* gout     = z_out + (size_t)N * 192;

    char* ws = (char*)d_ws;
    unsigned short* Ybf = (unsigned short*)ws; ws += (size_t)N * 128 * 2;
    unsigned short* Hbf = (unsigned short*)ws; ws += (size_t)N * 128 * 2;
    unsigned short* Zbf = (unsigned short*)ws; ws += (size_t)N * 64 * 2;
    int*   esrc  = (int*)ws;   ws += (size_t)(E + N) * 4;
    int*   offs  = (int*)ws;   ws += (size_t)(N + 1) * 4;
    float* dinv  = (float*)ws; ws += (size_t)N * 4;
    int*   gcnt  = (int*)ws;   ws += 256 * 8 * 4;
    int*   bbase = (int*)ws;   ws += 256 * 4;
    float* rvec  = (float*)ws; ws += (size_t)N * 4;
    float* Wc    = (float*)ws; ws += 128 * 128 * 4;
    float* Wd    = (float*)ws; ws += 64 * 128 * 4;
    float* bc    = (float*)ws; ws += 128 * 4;
    float* b2c   = (float*)ws; ws += 128 * 4;
    float* bd12  = (float*)ws; ws += 128 * 4;

    // `pairs` ALIASES Ybf+Hbf (CSR build completes before matmuls touch Ybf).
    uint2* pairs = (uint2*)Ybf;
    size_t pairRegion = (size_t)N * 128 * 2 * 2;
    int capS = 1536;
    int capMax = (int)(pairRegion / (256 * 8 * sizeof(uint2)));
    if (capS > capMax) capS = capMax;

    const int* src = ei;
    const int* dst = ei + E;
    int total = E + N;

    // ---- CSR build (coalesced counting sort) ----
    zero_kernel<<<(256 * 8 + 255) / 256, 256, 0, stream>>>(gcnt, 256 * 8);
    bucketize_kernel<<<(total + 4095) / 4096, 256, 0, stream>>>(
        src, dst, E, N, capS, pairs, gcnt);
    scan_bases_kernel<<<1, 256, 0, stream>>>(gcnt, nb, capS, bbase, offs, N);
    build_kernel<<<nb, 256, 0, stream>>>(pairs, gcnt, capS, bbase, N, offs,
                                         dinv, esrc);

    // ---- collapsed weights (tiny) ----
    wcomb_kernel<<<(16384 + 8192 + 384 + 255) / 256, 256, 0, stream>>>(
        W_enc, b_enc, W_mean, b_mean, W_lv, b_lv, W_d1, b_d1, W_d2,
        Wc, bc, b2c, Wd, bd12);

    int gx = (N + 63) / 64;
    int aggBlocks = (int)(((size_t)N * 64 + 255) / 256);

    // ---- encoder: meanlv = A^2 X Wc + r*bc + b2c ----
    matmul_kernel<128, false, true><<<dim3(gx, 2), 256, 0, stream>>>(
        feature, Wc, dinv, Ybf, N);                      // U = dinv*(X@Wc)
    agg_kernel<true, true><<<aggBlocks, 256, 0, stream>>>(
        Ybf, offs, esrc, dinv, Hbf, rvec, N);            // V = dinv*(A X Wc), r
    aggmeanlv_kernel<<<aggBlocks, 256, 0, stream>>>(
        Hbf, offs, esrc, dinv, rvec, bc, b2c, noise,
        mean_out, lv_out, z_out, Zbf, N);                // mean/lv/z + zb

    // ---- decoder: out = A^2 z Wd + r*bd12 + bd2 ----
    agg64_kernel<true><<<aggBlocks, 256, 0, stream>>>(
        Zbf, offs, esrc, dinv, Ybf, N);                  // P = dinv*(A z)
    agg64_kernel<false><<<aggBlocks, 256, 0, stream>>>(
        Ybf, offs, esrc, dinv, Hbf, N);                  // Q = A^2 z
    matmul_out_kernel<<<dim3(gx, 2), 256, 0, stream>>>(
        Hbf, Wd, rvec, bd12, b_d2, gout, N);             // out (fp32)
}

// Round 3
// 407.608 us; speedup vs baseline: 1.3786x; 1.1123x over previous
//
#include <hip/hip_runtime.h>
#include <math.h>

// ---------------------------------------------------------------------------
// GCN-VAE fused pipeline for MI355X.
// R9: gather MLP. R8 counters showed aggs latency-bound (HBM 36%, VALU 35%,
// occupancy 68% -- nothing saturated) with only 4 row-gathers in flight per
// wave. All three agg kernels now keep 8 gathers outstanding (8-unroll body,
// 4-tail, scalar tail). Matmuls/CSR build/numerics are the verified R8
// versions, untouched.
// ---------------------------------------------------------------------------

__device__ inline float bf2f_lo(unsigned int v) {
    return __uint_as_float(v << 16);
}
__device__ inline float bf2f_hi(unsigned int v) {
    return __uint_as_float(v & 0xFFFF0000u);
}
__device__ inline float bf2f(unsigned short u) {
    return __uint_as_float(((unsigned int)u) << 16);
}
__device__ inline unsigned short f2bf(float f) {
    unsigned int u = __float_as_uint(f);
    return (unsigned short)((u + 0x7FFFu + ((u >> 16) & 1u)) >> 16);
}
__device__ inline unsigned int get_xcd() {
    unsigned int x;
    asm volatile("s_getreg_b32 %0, hwreg(HW_REG_XCC_ID)" : "=s"(x));
    return x & 7u;
}

__global__ void zero_kernel(int* __restrict__ p, int n) {
    int i = blockIdx.x * blockDim.x + threadIdx.x;
    if (i < n) p[i] = 0;
}

// Pass 1: bucket edges (+self-loops) by dst>>8 into per-(bucket,XCD) slices.
__global__ __launch_bounds__(256) void bucketize_kernel(
    const int* __restrict__ src, const int* __restrict__ dst, int E, int N,
    int capS, uint2* __restrict__ pairs, int* __restrict__ gcnt) {
    __shared__ int lcnt[256];
    __shared__ int lbase[256];
    int tid = threadIdx.x;
    int total = E + N;
    int base = blockIdx.x * 4096;
    unsigned int x = get_xcd();
    lcnt[tid] = 0;
    __syncthreads();
    int d[16], s[16], rk[16];
#pragma unroll
    for (int j = 0; j < 16; j++) {
        int idx = base + j * 256 + tid;
        d[j] = -1;
        if (idx < total) {
            if (idx < E) { d[j] = dst[idx]; s[j] = src[idx]; }
            else         { d[j] = idx - E; s[j] = d[j]; }
            rk[j] = atomicAdd(&lcnt[d[j] >> 8], 1);
        }
    }
    __syncthreads();
    if (lcnt[tid] > 0) lbase[tid] = atomicAdd(&gcnt[tid * 8 + (int)x],
                                              lcnt[tid]);
    __syncthreads();
#pragma unroll
    for (int j = 0; j < 16; j++) {
        if (d[j] >= 0) {
            int b = d[j] >> 8;
            int pos = lbase[b] + rk[j];
            if (pos < capS)
                pairs[(size_t)(b * 8 + (int)x) * capS + pos] =
                    make_uint2((unsigned)d[j], (unsigned)s[j]);
        }
    }
}

// Pass 2: scan bucket totals -> bucket bases; offs[N] = grand total.
__global__ __launch_bounds__(256) void scan_bases_kernel(
    const int* __restrict__ gcnt, int nb, int capS, int* __restrict__ bbase,
    int* __restrict__ offs, int N) {
    __shared__ int lds[256];
    int tid = threadIdx.x;
    int t = 0;
    if (tid < nb) {
#pragma unroll
        for (int x = 0; x < 8; x++) {
            int v = gcnt[tid * 8 + x];
            if (v > capS) v = capS;
            t += v;
        }
    }
    lds[tid] = t;
    __syncthreads();
    for (int off = 1; off < 256; off <<= 1) {
        int u = (tid >= off) ? lds[tid - off] : 0;
        __syncthreads();
        lds[tid] += u;
        __syncthreads();
    }
    bbase[tid] = lds[tid] - t;
    if (tid == 255) offs[N] = lds[255];
}

// Pass 3: one block per bucket; LDS counting sort by dst&255; coalesced out.
__global__ __launch_bounds__(256) void build_kernel(
    const uint2* __restrict__ pairs, const int* __restrict__ gcnt, int capS,
    const int* __restrict__ bbase, int N, int* __restrict__ offs,
    float* __restrict__ dinv, int* __restrict__ esrc) {
    __shared__ int cnt[256];
    __shared__ int loff[256];
    __shared__ int cur[256];
    __shared__ int S[10240];
    int b = blockIdx.x;
    int tid = threadIdx.x;
    cnt[tid] = 0;
    __syncthreads();
    int szx[8];
#pragma unroll
    for (int x = 0; x < 8; x++) {
        int v = gcnt[b * 8 + x];
        if (v > capS) v = capS;
        szx[x] = v;
    }
#pragma unroll
    for (int x = 0; x < 8; x++) {
        const uint2* bp = pairs + (size_t)(b * 8 + x) * capS;
        for (int i = tid; i < szx[x]; i += 256)
            atomicAdd(&cnt[bp[i].x & 255u], 1);
    }
    __syncthreads();
    int c = cnt[tid];
    loff[tid] = c;
    __syncthreads();
    for (int off = 1; off < 256; off <<= 1) {
        int u = (tid >= off) ? loff[tid - off] : 0;
        __syncthreads();
        loff[tid] += u;
        __syncthreads();
    }
    int excl = loff[tid] - c;
    cur[tid] = excl;
    int total = loff[255];
    int base = bbase[b];
    int d0 = b << 8;
    if (d0 + tid < N) {
        offs[d0 + tid] = base + excl;
        dinv[d0 + tid] = rsqrtf((float)c);   // c >= 1 (self-loop)
    }
    __syncthreads();
#pragma unroll
    for (int x = 0; x < 8; x++) {
        const uint2* bp = pairs + (size_t)(b * 8 + x) * capS;
        for (int i = tid; i < szx[x]; i += 256) {
            uint2 p = bp[i];
            int pos = atomicAdd(&cur[p.x & 255u], 1);
            if (pos < 10240) S[pos] = (int)p.y;
        }
    }
    __syncthreads();
    if (total > 10240) total = 10240;
    for (int j = tid; j < total; j += 256) esrc[base + j] = S[j];
}

// Collapse weights on-device (tiny):
//  Wc[k][2j]=sum_m We[k][m]*Wm[m][j], Wc[k][2j+1]=sum_m We[k][m]*Wl[m][j]
//  Wd[k][c]=sum_m Wd1[k][m]*Wd2[m][c]
//  bc[2j]=be@Wm, bc[2j+1]=be@Wl; b2c = interleave(bm,bl); bd12 = bd1@Wd2
__global__ __launch_bounds__(256) void wcomb_kernel(
    const float* __restrict__ We, const float* __restrict__ be,
    const float* __restrict__ Wm, const float* __restrict__ bm,
    const float* __restrict__ Wl, const float* __restrict__ bl,
    const float* __restrict__ Wd1, const float* __restrict__ bd1,
    const float* __restrict__ Wd2, float* __restrict__ Wc,
    float* __restrict__ bc, float* __restrict__ b2c, float* __restrict__ Wd,
    float* __restrict__ bd12) {
    int i = blockIdx.x * 256 + threadIdx.x;
    if (i < 16384) {                          // Wc (128x128 interleaved)
        int k = i >> 7, c = i & 127, j = c >> 1;
        const float* Wx = (c & 1) ? Wl : Wm;
        float s = 0.f;
        for (int m = 0; m < 128; m++) s += We[k * 128 + m] * Wx[m * 64 + j];
        Wc[k * 128 + c] = s;
    } else if (i < 16384 + 8192) {            // Wd (64x128)
        int t = i - 16384;
        int k = t >> 7, c = t & 127;
        float s = 0.f;
        for (int m = 0; m < 128; m++) s += Wd1[k * 128 + m] * Wd2[m * 128 + c];
        Wd[k * 128 + c] = s;
    } else if (i < 16384 + 8192 + 128) {      // bc
        int c = i - (16384 + 8192), j = c >> 1;
        const float* Wx = (c & 1) ? Wl : Wm;
        float s = 0.f;
        for (int m = 0; m < 128; m++) s += be[m] * Wx[m * 64 + j];
        bc[c] = s;
    } else if (i < 16384 + 8192 + 256) {      // b2c
        int c = i - (16384 + 8192 + 128);
        b2c[c] = (c & 1) ? bl[c >> 1] : bm[c >> 1];
    } else if (i < 16384 + 8192 + 384) {      // bd12
        int c = i - (16384 + 8192 + 256);
        float s = 0.f;
        for (int m = 0; m < 128; m++) s += bd1[m] * Wd2[m * 128 + c];
        bd12[c] = s;
    }
}

// Tiled matmul: out[N,128] = X[N,K] @ W[K,128], bf16 out, dinv row prescale.
// launch_bounds(256,4): cap VGPR at 128 so the scheduler keeps >=4 w/SIMD.
// ldsX padded +4 floats: per-wave row reads land 2-way (free) not 4-way.
template <int K, bool XBF, bool SCALE>
__global__ __launch_bounds__(256, 4) void matmul_kernel(
    const void* __restrict__ Xv, const float* __restrict__ W,
    const float* __restrict__ dinv, unsigned short* __restrict__ out, int N) {
    const int M = 128;
    const int KP = K + 4;
    __shared__ float ldsW[K][64];
    __shared__ float ldsX[64][KP];
    int tid = threadIdx.x;
    int row0 = blockIdx.x * 64;
    int col0 = blockIdx.y * 64;

    for (int i = tid; i < K * 16; i += 256) {
        int k = i >> 4, j4 = i & 15;
        ((float4*)&ldsW[k][0])[j4] =
            *(const float4*)&W[(size_t)k * M + col0 + j4 * 4];
    }
    int maxr = N - row0; if (maxr > 64) maxr = 64;
    if (XBF) {
        const unsigned short* X = (const unsigned short*)Xv;
        for (int i = tid; i < maxr * (K / 8); i += 256) {
            int r = i / (K / 8), c8 = i % (K / 8);
            uint4 u = *(const uint4*)&X[(size_t)(row0 + r) * K + c8 * 8];
            float* dp = &ldsX[r][c8 * 8];
            dp[0] = bf2f_lo(u.x); dp[1] = bf2f_hi(u.x);
            dp[2] = bf2f_lo(u.y); dp[3] = bf2f_hi(u.y);
            dp[4] = bf2f_lo(u.z); dp[5] = bf2f_hi(u.z);
            dp[6] = bf2f_lo(u.w); dp[7] = bf2f_hi(u.w);
        }
    } else {
        const float* X = (const float*)Xv;
        for (int i = tid; i < maxr * (K / 4); i += 256) {
            int r = i / (K / 4), k4 = i % (K / 4);
            *(float4*)&ldsX[r][k4 * 4] =
                *(const float4*)&X[(size_t)(row0 + r) * K + k4 * 4];
        }
    }
    __syncthreads();

    int cg = tid & 15, rg = tid >> 4;
    int rbase = rg * 4, cbase = cg * 4;
    float acc[4][4] = {};
#pragma unroll 2
    for (int k = 0; k < K; k += 4) {
        float4 xv[4];
#pragma unroll
        for (int r = 0; r < 4; r++)
            xv[r] = *(const float4*)&ldsX[rbase + r][k];
        const float* xp = (const float*)xv;
#pragma unroll
        for (int kk = 0; kk < 4; kk++) {
            float4 wv = *(const float4*)&ldsW[k + kk][cbase];
#pragma unroll
            for (int r = 0; r < 4; r++) {
                float xs = xp[r * 4 + kk];
                acc[r][0] += xs * wv.x;
                acc[r][1] += xs * wv.y;
                acc[r][2] += xs * wv.z;
                acc[r][3] += xs * wv.w;
            }
        }
    }
#pragma unroll
    for (int r = 0; r < 4; r++) {
        int row = row0 + rbase + r;
        if (row < N) {
            float sc = SCALE ? dinv[row] : 1.0f;
            ushort4 o;
            o.x = f2bf(acc[r][0] * sc); o.y = f2bf(acc[r][1] * sc);
            o.z = f2bf(acc[r][2] * sc); o.w = f2bf(acc[r][3] * sc);
            *(ushort4*)&out[(size_t)row * M + col0 + cbase] = o;
        }
    }
}

// Final matmul: out[N,128] = Q[N,64]@Wd + r[row]*b1[col] + b2[col], fp32 out.
__global__ __launch_bounds__(256, 4) void matmul_out_kernel(
    const unsigned short* __restrict__ X, const float* __restrict__ W,
    const float* __restrict__ rvec, const float* __restrict__ b1,
    const float* __restrict__ b2, float* __restrict__ out, int N) {
    const int K = 64, M = 128;
    const int KP = K + 4;
    __shared__ float ldsW[K][64];
    __shared__ float ldsX[64][KP];
    int tid = threadIdx.x;
    int row0 = blockIdx.x * 64;
    int col0 = blockIdx.y * 64;

    for (int i = tid; i < K * 16; i += 256) {
        int k = i >> 4, j4 = i & 15;
        ((float4*)&ldsW[k][0])[j4] =
            *(const float4*)&W[(size_t)k * M + col0 + j4 * 4];
    }
    int maxr = N - row0; if (maxr > 64) maxr = 64;
    for (int i = tid; i < maxr * (K / 8); i += 256) {
        int r = i / (K / 8), c8 = i % (K / 8);
        uint4 u = *(const uint4*)&X[(size_t)(row0 + r) * K + c8 * 8];
        float* dp = &ldsX[r][c8 * 8];
        dp[0] = bf2f_lo(u.x); dp[1] = bf2f_hi(u.x);
        dp[2] = bf2f_lo(u.y); dp[3] = bf2f_hi(u.y);
        dp[4] = bf2f_lo(u.z); dp[5] = bf2f_hi(u.z);
        dp[6] = bf2f_lo(u.w); dp[7] = bf2f_hi(u.w);
    }
    __syncthreads();

    int cg = tid & 15, rg = tid >> 4;
    int rbase = rg * 4, cbase = cg * 4;
    float acc[4][4] = {};
#pragma unroll 2
    for (int k = 0; k < K; k += 4) {
        float4 xv[4];
#pragma unroll
        for (int r = 0; r < 4; r++)
            xv[r] = *(const float4*)&ldsX[rbase + r][k];
        const float* xp = (const float*)xv;
#pragma unroll
        for (int kk = 0; kk < 4; kk++) {
            float4 wv = *(const float4*)&ldsW[k + kk][cbase];
#pragma unroll
            for (int r = 0; r < 4; r++) {
                float xs = xp[r * 4 + kk];
                acc[r][0] += xs * wv.x;
                acc[r][1] += xs * wv.y;
                acc[r][2] += xs * wv.z;
                acc[r][3] += xs * wv.w;
            }
        }
    }
    float4 b1v = *(const float4*)&b1[col0 + cbase];
    float4 b2v = *(const float4*)&b2[col0 + cbase];
#pragma unroll
    for (int r = 0; r < 4; r++) {
        int row = row0 + rbase + r;
        if (row < N) {
            float rr = rvec[row];
            float4 o = make_float4(acc[r][0] + rr * b1v.x + b2v.x,
                                   acc[r][1] + rr * b1v.y + b2v.y,
                                   acc[r][2] + rr * b1v.z + b2v.z,
                                   acc[r][3] + rr * b1v.w + b2v.w);
            *(float4*)&out[(size_t)row * M + col0 + cbase] = o;
        }
    }
}

// 128-col aggregation over dinv-prescaled bf16 rows. One wave per dst; lane
// owns cols {2*lane, 2*lane+1}. 8 row-gathers kept in flight (R9).
// WR: also emit r[d] = dinv[d]*sum(dinv[src]) (rank-1 bias vector, = A*ones).
template <bool PRE, bool WR>
__global__ __launch_bounds__(256) void agg_kernel(
    const unsigned short* __restrict__ Y, const int* __restrict__ offsets,
    const int* __restrict__ esrc, const float* __restrict__ dinv,
    unsigned short* __restrict__ out, float* __restrict__ rout, int N) {
    int wid = (blockIdx.x * blockDim.x + threadIdx.x) >> 6;
    int lane = threadIdx.x & 63;
    if (wid >= N) return;
    int beg = offsets[wid], end = offsets[wid + 1];
    const unsigned int* Yu = (const unsigned int*)Y;  // ushort2 pairs
    float ax = 0.f, ay = 0.f, ad = 0.f;
    int e = beg;
    for (; e + 8 <= end; e += 8) {
        int ss[8];
#pragma unroll
        for (int j = 0; j < 8; j++) ss[j] = esrc[e + j];
        unsigned int vv[8];
#pragma unroll
        for (int j = 0; j < 8; j++) vv[j] = Yu[(size_t)ss[j] * 64 + lane];
        if (WR) {
#pragma unroll
            for (int j = 0; j < 8; j++) ad += dinv[ss[j]];
        }
#pragma unroll
        for (int j = 0; j < 8; j++) {
            ax += bf2f_lo(vv[j]);
            ay += bf2f_hi(vv[j]);
        }
    }
    for (; e + 4 <= end; e += 4) {
        int s0 = esrc[e], s1 = esrc[e + 1], s2 = esrc[e + 2], s3 = esrc[e + 3];
        unsigned int v0 = Yu[(size_t)s0 * 64 + lane];
        unsigned int v1 = Yu[(size_t)s1 * 64 + lane];
        unsigned int v2 = Yu[(size_t)s2 * 64 + lane];
        unsigned int v3 = Yu[(size_t)s3 * 64 + lane];
        if (WR) ad += dinv[s0] + dinv[s1] + dinv[s2] + dinv[s3];
        ax += bf2f_lo(v0) + bf2f_lo(v1) + bf2f_lo(v2) + bf2f_lo(v3);
        ay += bf2f_hi(v0) + bf2f_hi(v1) + bf2f_hi(v2) + bf2f_hi(v3);
    }
    for (; e < end; e++) {
        int s0 = esrc[e];
        unsigned int v0 = Yu[(size_t)s0 * 64 + lane];
        if (WR) ad += dinv[s0];
        ax += bf2f_lo(v0);
        ay += bf2f_hi(v0);
    }
    float dd = dinv[wid];
    float rx = ax * dd, ry = ay * dd;
    if (PRE) { rx *= dd; ry *= dd; }
    unsigned int packed = (unsigned int)f2bf(rx) |
                          ((unsigned int)f2bf(ry) << 16);
    ((unsigned int*)out)[(size_t)wid * 64 + lane] = packed;
    if (WR && lane == 0) rout[wid] = ad * dd;
}

// Second encoder agg + fused VAE head epilogue.  Input V = dinv*(A X Wc)
// with Wc columns interleaved (even=mean-path, odd=lv-path); lane j holds
// (T_mean[j], T_lv[j]).  mean = T + r*bc + b2c; z = noise*exp(.5 lv)+mean;
// zb = dinv*z (bf16, prescaled for the decoder aggregation chain).
__global__ __launch_bounds__(256) void aggmeanlv_kernel(
    const unsigned short* __restrict__ Y, const int* __restrict__ offsets,
    const int* __restrict__ esrc, const float* __restrict__ dinv,
    const float* __restrict__ rvec, const float* __restrict__ bc,
    const float* __restrict__ b2c, const float* __restrict__ noise,
    float* __restrict__ mean, float* __restrict__ lv, float* __restrict__ z,
    unsigned short* __restrict__ zb, int N) {
    int wid = (blockIdx.x * blockDim.x + threadIdx.x) >> 6;
    int lane = threadIdx.x & 63;
    if (wid >= N) return;
    int beg = offsets[wid], end = offsets[wid + 1];
    const unsigned int* Yu = (const unsigned int*)Y;
    float ax = 0.f, ay = 0.f;
    int e = beg;
    for (; e + 8 <= end; e += 8) {
        int ss[8];
#pragma unroll
        for (int j = 0; j < 8; j++) ss[j] = esrc[e + j];
        unsigned int vv[8];
#pragma unroll
        for (int j = 0; j < 8; j++) vv[j] = Yu[(size_t)ss[j] * 64 + lane];
#pragma unroll
        for (int j = 0; j < 8; j++) {
            ax += bf2f_lo(vv[j]);
            ay += bf2f_hi(vv[j]);
        }
    }
    for (; e + 4 <= end; e += 4) {
        int s0 = esrc[e], s1 = esrc[e + 1], s2 = esrc[e + 2], s3 = esrc[e + 3];
        unsigned int v0 = Yu[(size_t)s0 * 64 + lane];
        unsigned int v1 = Yu[(size_t)s1 * 64 + lane];
        unsigned int v2 = Yu[(size_t)s2 * 64 + lane];
        unsigned int v3 = Yu[(size_t)s3 * 64 + lane];
        ax += bf2f_lo(v0) + bf2f_lo(v1) + bf2f_lo(v2) + bf2f_lo(v3);
        ay += bf2f_hi(v0) + bf2f_hi(v1) + bf2f_hi(v2) + bf2f_hi(v3);
    }
    for (; e < end; e++) {
        unsigned int v0 = Yu[(size_t)esrc[e] * 64 + lane];
        ax += bf2f_lo(v0);
        ay += bf2f_hi(v0);
    }
    float dd = dinv[wid];
    float rr = rvec[wid];
    float2 bcv = ((const float2*)bc)[lane];
    float2 b2v = ((const float2*)b2c)[lane];
    float m = ax * dd + rr * bcv.x + b2v.x;
    float l = ay * dd + rr * bcv.y + b2v.y;
    float nv = noise[(size_t)wid * 64 + lane];
    float zv = nv * expf(0.5f * l) + m;
    size_t o = (size_t)wid * 64 + lane;
    mean[o] = m;
    lv[o] = l;
    z[o] = zv;
    zb[o] = f2bf(zv * dd);
}

// 64-col aggregation (decoder, z-space): lane owns one bf16 column; each
// edge gathers one 128 B row. 8 gathers in flight (R9).
template <bool PRE>
__global__ __launch_bounds__(256) void agg64_kernel(
    const unsigned short* __restrict__ Y, const int* __restrict__ offsets,
    const int* __restrict__ esrc, const float* __restrict__ dinv,
    unsigned short* __restrict__ out, int N) {
    int wid = (blockIdx.x * blockDim.x + threadIdx.x) >> 6;
    int lane = threadIdx.x & 63;
    if (wid >= N) return;
    int beg = offsets[wid], end = offsets[wid + 1];
    float ax = 0.f;
    int e = beg;
    for (; e + 8 <= end; e += 8) {
        int ss[8];
#pragma unroll
        for (int j = 0; j < 8; j++) ss[j] = esrc[e + j];
        unsigned short vv[8];
#pragma unroll
        for (int j = 0; j < 8; j++) vv[j] = Y[(size_t)ss[j] * 64 + lane];
#pragma unroll
        for (int j = 0; j < 8; j++) ax += bf2f(vv[j]);
    }
    for (; e + 4 <= end; e += 4) {
        int s0 = esrc[e], s1 = esrc[e + 1], s2 = esrc[e + 2], s3 = esrc[e + 3];
        unsigned short v0 = Y[(size_t)s0 * 64 + lane];
        unsigned short v1 = Y[(size_t)s1 * 64 + lane];
        unsigned short v2 = Y[(size_t)s2 * 64 + lane];
        unsigned short v3 = Y[(size_t)s3 * 64 + lane];
        ax += bf2f(v0) + bf2f(v1) + bf2f(v2) + bf2f(v3);
    }
    for (; e < end; e++) {
        ax += bf2f(Y[(size_t)esrc[e] * 64 + lane]);
    }
    float dd = dinv[wid];
    float rx = ax * dd;
    if (PRE) rx *= dd;
    out[(size_t)wid * 64 + lane] = f2bf(rx);
}

extern "C" void kernel_launch(void* const* d_in, const int* in_sizes, int n_in,
                              void* d_out, int out_size, void* d_ws,
                              size_t ws_size, hipStream_t stream) {
    const float* feature = (const float*)d_in[0];
    const int*   ei      = (const int*)d_in[1];
    const float* noise   = (const float*)d_in[2];
    const float* W_enc   = (const float*)d_in[3];
    const float* b_enc   = (const float*)d_in[4];
    const float* W_mean  = (const float*)d_in[5];
    const float* b_mean  = (const float*)d_in[6];
    const float* W_lv    = (const float*)d_in[7];
    const float* b_lv    = (const float*)d_in[8];
    const float* W_d1    = (const float*)d_in[9];
    const float* b_d1    = (const float*)d_in[10];
    const float* W_d2    = (const float*)d_in[11];
    const float* b_d2    = (const float*)d_in[12];

    int N = in_sizes[0] / 128;
    int E = in_sizes[1] / 2;
    int nb = (N + 255) >> 8;

    float* z_out    = (float*)d_out;
    float* mean_out = z_out + (size_t)N * 64;
    float* lv_out   = z_out + (size_t)N * 128;
    float* gout     = z_out + (size_t)N * 192;

    char* ws = (char*)d_ws;
    unsigned short* Ybf = (unsigned short*)ws; ws += (size_t)N * 128 * 2;
    unsigned short* Hbf = (unsigned short*)ws; ws += (size_t)N * 128 * 2;
    unsigned short* Zbf = (unsigned short*)ws; ws += (size_t)N * 64 * 2;
    int*   esrc  = (int*)ws;   ws += (size_t)(E + N) * 4;
    int*   offs  = (int*)ws;   ws += (size_t)(N + 1) * 4;
    float* dinv  = (float*)ws; ws += (size_t)N * 4;
    int*   gcnt  = (int*)ws;   ws += 256 * 8 * 4;
    int*   bbase = (int*)ws;   ws += 256 * 4;
    float* rvec  = (float*)ws; ws += (size_t)N * 4;
    float* Wc    = (float*)ws; ws += 128 * 128 * 4;
    float* Wd    = (float*)ws; ws += 64 * 128 * 4;
    float* bc    = (float*)ws; ws += 128 * 4;
    float* b2c   = (float*)ws; ws += 128 * 4;
    float* bd12  = (float*)ws; ws += 128 * 4;

    // `pairs` ALIASES Ybf+Hbf (CSR build completes before matmuls touch Ybf).
    uint2* pairs = (uint2*)Ybf;
    size_t pairRegion = (size_t)N * 128 * 2 * 2;
    int capS = 1536;
    int capMax = (int)(pairRegion / (256 * 8 * sizeof(uint2)));
    if (capS > capMax) capS = capMax;

    const int* src = ei;
    const int* dst = ei + E;
    int total = E + N;

    // ---- CSR build (coalesced counting sort) ----
    zero_kernel<<<(256 * 8 + 255) / 256, 256, 0, stream>>>(gcnt, 256 * 8);
    bucketize_kernel<<<(total + 4095) / 4096, 256, 0, stream>>>(
        src, dst, E, N, capS, pairs, gcnt);
    scan_bases_kernel<<<1, 256, 0, stream>>>(gcnt, nb, capS, bbase, offs, N);
    build_kernel<<<nb, 256, 0, stream>>>(pairs, gcnt, capS, bbase, N, offs,
                                         dinv, esrc);

    // ---- collapsed weights (tiny) ----
    wcomb_kernel<<<(16384 + 8192 + 384 + 255) / 256, 256, 0, stream>>>(
        W_enc, b_enc, W_mean, b_mean, W_lv, b_lv, W_d1, b_d1, W_d2,
        Wc, bc, b2c, Wd, bd12);

    int gx = (N + 63) / 64;
    int aggBlocks = (int)(((size_t)N * 64 + 255) / 256);

    // ---- encoder: meanlv = A^2 X Wc + r*bc + b2c ----
    matmul_kernel<128, false, true><<<dim3(gx, 2), 256, 0, stream>>>(
        feature, Wc, dinv, Ybf, N);                      // U = dinv*(X@Wc)
    agg_kernel<true, true><<<aggBlocks, 256, 0, stream>>>(
        Ybf, offs, esrc, dinv, Hbf, rvec, N);            // V = dinv*(A X Wc), r
    aggmeanlv_kernel<<<aggBlocks, 256, 0, stream>>>(
        Hbf, offs, esrc, dinv, rvec, bc, b2c, noise,
        mean_out, lv_out, z_out, Zbf, N);                // mean/lv/z + zb

    // ---- decoder: out = A^2 z Wd + r*bd12 + bd2 ----
    agg64_kernel<true><<<aggBlocks, 256, 0, stream>>>(
        Zbf, offs, esrc, dinv, Ybf, N);                  // P = dinv*(A z)
    agg64_kernel<false><<<aggBlocks, 256, 0, stream>>>(
        Ybf, offs, esrc, dinv, Hbf, N);                  // Q = A^2 z
    matmul_out_kernel<<<dim3(gx, 2), 256, 0, stream>>>(
        Hbf, Wd, rvec, bd12, b_d2, gout, N);             // out (fp32)
}

// Round 4
// 395.614 us; speedup vs baseline: 1.4204x; 1.0303x over previous
//
#include <hip/hip_runtime.h>
#include <math.h>

// ---------------------------------------------------------------------------
// GCN-VAE fused pipeline for MI355X.
// R10: half-wave row-split gathers. R9 showed aggs still co-limited by
// latency + per-edge instruction count (HBM 42%, VALU 40%, nothing
// saturated) with 4 B/lane gathers. Now each lane gathers 8 B (uint2):
// 128-col aggs split the wave into 2 half-waves handling edges e/e+1
// (one load instruction = 2 rows = 512 B); 64-col aggs use 4 quarter-waves
// (one load = 4 rows). Parities combine via __shfl_xor at the end.
// 16 edges in flight per wave. Matmuls / CSR build / numerics = verified R9.
// ---------------------------------------------------------------------------

__device__ inline float bf2f_lo(unsigned int v) {
    return __uint_as_float(v << 16);
}
__device__ inline float bf2f_hi(unsigned int v) {
    return __uint_as_float(v & 0xFFFF0000u);
}
__device__ inline unsigned short f2bf(float f) {
    unsigned int u = __float_as_uint(f);
    return (unsigned short)((u + 0x7FFFu + ((u >> 16) & 1u)) >> 16);
}
__device__ inline unsigned int get_xcd() {
    unsigned int x;
    asm volatile("s_getreg_b32 %0, hwreg(HW_REG_XCC_ID)" : "=s"(x));
    return x & 7u;
}

__global__ void zero_kernel(int* __restrict__ p, int n) {
    int i = blockIdx.x * blockDim.x + threadIdx.x;
    if (i < n) p[i] = 0;
}

// Pass 1: bucket edges (+self-loops) by dst>>8 into per-(bucket,XCD) slices.
__global__ __launch_bounds__(256) void bucketize_kernel(
    const int* __restrict__ src, const int* __restrict__ dst, int E, int N,
    int capS, uint2* __restrict__ pairs, int* __restrict__ gcnt) {
    __shared__ int lcnt[256];
    __shared__ int lbase[256];
    int tid = threadIdx.x;
    int total = E + N;
    int base = blockIdx.x * 4096;
    unsigned int x = get_xcd();
    lcnt[tid] = 0;
    __syncthreads();
    int d[16], s[16], rk[16];
#pragma unroll
    for (int j = 0; j < 16; j++) {
        int idx = base + j * 256 + tid;
        d[j] = -1;
        if (idx < total) {
            if (idx < E) { d[j] = dst[idx]; s[j] = src[idx]; }
            else         { d[j] = idx - E; s[j] = d[j]; }
            rk[j] = atomicAdd(&lcnt[d[j] >> 8], 1);
        }
    }
    __syncthreads();
    if (lcnt[tid] > 0) lbase[tid] = atomicAdd(&gcnt[tid * 8 + (int)x],
                                              lcnt[tid]);
    __syncthreads();
#pragma unroll
    for (int j = 0; j < 16; j++) {
        if (d[j] >= 0) {
            int b = d[j] >> 8;
            int pos = lbase[b] + rk[j];
            if (pos < capS)
                pairs[(size_t)(b * 8 + (int)x) * capS + pos] =
                    make_uint2((unsigned)d[j], (unsigned)s[j]);
        }
    }
}

// Pass 2: scan bucket totals -> bucket bases; offs[N] = grand total.
__global__ __launch_bounds__(256) void scan_bases_kernel(
    const int* __restrict__ gcnt, int nb, int capS, int* __restrict__ bbase,
    int* __restrict__ offs, int N) {
    __shared__ int lds[256];
    int tid = threadIdx.x;
    int t = 0;
    if (tid < nb) {
#pragma unroll
        for (int x = 0; x < 8; x++) {
            int v = gcnt[tid * 8 + x];
            if (v > capS) v = capS;
            t += v;
        }
    }
    lds[tid] = t;
    __syncthreads();
    for (int off = 1; off < 256; off <<= 1) {
        int u = (tid >= off) ? lds[tid - off] : 0;
        __syncthreads();
        lds[tid] += u;
        __syncthreads();
    }
    bbase[tid] = lds[tid] - t;
    if (tid == 255) offs[N] = lds[255];
}

// Pass 3: one block per bucket; LDS counting sort by dst&255; coalesced out.
__global__ __launch_bounds__(256) void build_kernel(
    const uint2* __restrict__ pairs, const int* __restrict__ gcnt, int capS,
    const int* __restrict__ bbase, int N, int* __restrict__ offs,
    float* __restrict__ dinv, int* __restrict__ esrc) {
    __shared__ int cnt[256];
    __shared__ int loff[256];
    __shared__ int cur[256];
    __shared__ int S[10240];
    int b = blockIdx.x;
    int tid = threadIdx.x;
    cnt[tid] = 0;
    __syncthreads();
    int szx[8];
#pragma unroll
    for (int x = 0; x < 8; x++) {
        int v = gcnt[b * 8 + x];
        if (v > capS) v = capS;
        szx[x] = v;
    }
#pragma unroll
    for (int x = 0; x < 8; x++) {
        const uint2* bp = pairs + (size_t)(b * 8 + x) * capS;
        for (int i = tid; i < szx[x]; i += 256)
            atomicAdd(&cnt[bp[i].x & 255u], 1);
    }
    __syncthreads();
    int c = cnt[tid];
    loff[tid] = c;
    __syncthreads();
    for (int off = 1; off < 256; off <<= 1) {
        int u = (tid >= off) ? loff[tid - off] : 0;
        __syncthreads();
        loff[tid] += u;
        __syncthreads();
    }
    int excl = loff[tid] - c;
    cur[tid] = excl;
    int total = loff[255];
    int base = bbase[b];
    int d0 = b << 8;
    if (d0 + tid < N) {
        offs[d0 + tid] = base + excl;
        dinv[d0 + tid] = rsqrtf((float)c);   // c >= 1 (self-loop)
    }
    __syncthreads();
#pragma unroll
    for (int x = 0; x < 8; x++) {
        const uint2* bp = pairs + (size_t)(b * 8 + x) * capS;
        for (int i = tid; i < szx[x]; i += 256) {
            uint2 p = bp[i];
            int pos = atomicAdd(&cur[p.x & 255u], 1);
            if (pos < 10240) S[pos] = (int)p.y;
        }
    }
    __syncthreads();
    if (total > 10240) total = 10240;
    for (int j = tid; j < total; j += 256) esrc[base + j] = S[j];
}

// Collapse weights on-device (tiny):
//  Wc[k][2j]=sum_m We[k][m]*Wm[m][j], Wc[k][2j+1]=sum_m We[k][m]*Wl[m][j]
//  Wd[k][c]=sum_m Wd1[k][m]*Wd2[m][c]
//  bc[2j]=be@Wm, bc[2j+1]=be@Wl; b2c = interleave(bm,bl); bd12 = bd1@Wd2
__global__ __launch_bounds__(256) void wcomb_kernel(
    const float* __restrict__ We, const float* __restrict__ be,
    const float* __restrict__ Wm, const float* __restrict__ bm,
    const float* __restrict__ Wl, const float* __restrict__ bl,
    const float* __restrict__ Wd1, const float* __restrict__ bd1,
    const float* __restrict__ Wd2, float* __restrict__ Wc,
    float* __restrict__ bc, float* __restrict__ b2c, float* __restrict__ Wd,
    float* __restrict__ bd12) {
    int i = blockIdx.x * 256 + threadIdx.x;
    if (i < 16384) {                          // Wc (128x128 interleaved)
        int k = i >> 7, c = i & 127, j = c >> 1;
        const float* Wx = (c & 1) ? Wl : Wm;
        float s = 0.f;
        for (int m = 0; m < 128; m++) s += We[k * 128 + m] * Wx[m * 64 + j];
        Wc[k * 128 + c] = s;
    } else if (i < 16384 + 8192) {            // Wd (64x128)
        int t = i - 16384;
        int k = t >> 7, c = t & 127;
        float s = 0.f;
        for (int m = 0; m < 128; m++) s += Wd1[k * 128 + m] * Wd2[m * 128 + c];
        Wd[k * 128 + c] = s;
    } else if (i < 16384 + 8192 + 128) {      // bc
        int c = i - (16384 + 8192), j = c >> 1;
        const float* Wx = (c & 1) ? Wl : Wm;
        float s = 0.f;
        for (int m = 0; m < 128; m++) s += be[m] * Wx[m * 64 + j];
        bc[c] = s;
    } else if (i < 16384 + 8192 + 256) {      // b2c
        int c = i - (16384 + 8192 + 128);
        b2c[c] = (c & 1) ? bl[c >> 1] : bm[c >> 1];
    } else if (i < 16384 + 8192 + 384) {      // bd12
        int c = i - (16384 + 8192 + 256);
        float s = 0.f;
        for (int m = 0; m < 128; m++) s += bd1[m] * Wd2[m * 128 + c];
        bd12[c] = s;
    }
}

// Tiled matmul: out[N,128] = X[N,K] @ W[K,128], bf16 out, dinv row prescale.
template <int K, bool XBF, bool SCALE>
__global__ __launch_bounds__(256, 4) void matmul_kernel(
    const void* __restrict__ Xv, const float* __restrict__ W,
    const float* __restrict__ dinv, unsigned short* __restrict__ out, int N) {
    const int M = 128;
    const int KP = K + 4;
    __shared__ float ldsW[K][64];
    __shared__ float ldsX[64][KP];
    int tid = threadIdx.x;
    int row0 = blockIdx.x * 64;
    int col0 = blockIdx.y * 64;

    for (int i = tid; i < K * 16; i += 256) {
        int k = i >> 4, j4 = i & 15;
        ((float4*)&ldsW[k][0])[j4] =
            *(const float4*)&W[(size_t)k * M + col0 + j4 * 4];
    }
    int maxr = N - row0; if (maxr > 64) maxr = 64;
    if (XBF) {
        const unsigned short* X = (const unsigned short*)Xv;
        for (int i = tid; i < maxr * (K / 8); i += 256) {
            int r = i / (K / 8), c8 = i % (K / 8);
            uint4 u = *(const uint4*)&X[(size_t)(row0 + r) * K + c8 * 8];
            float* dp = &ldsX[r][c8 * 8];
            dp[0] = bf2f_lo(u.x); dp[1] = bf2f_hi(u.x);
            dp[2] = bf2f_lo(u.y); dp[3] = bf2f_hi(u.y);
            dp[4] = bf2f_lo(u.z); dp[5] = bf2f_hi(u.z);
            dp[6] = bf2f_lo(u.w); dp[7] = bf2f_hi(u.w);
        }
    } else {
        const float* X = (const float*)Xv;
        for (int i = tid; i < maxr * (K / 4); i += 256) {
            int r = i / (K / 4), k4 = i % (K / 4);
            *(float4*)&ldsX[r][k4 * 4] =
                *(const float4*)&X[(size_t)(row0 + r) * K + k4 * 4];
        }
    }
    __syncthreads();

    int cg = tid & 15, rg = tid >> 4;
    int rbase = rg * 4, cbase = cg * 4;
    float acc[4][4] = {};
#pragma unroll 2
    for (int k = 0; k < K; k += 4) {
        float4 xv[4];
#pragma unroll
        for (int r = 0; r < 4; r++)
            xv[r] = *(const float4*)&ldsX[rbase + r][k];
        const float* xp = (const float*)xv;
#pragma unroll
        for (int kk = 0; kk < 4; kk++) {
            float4 wv = *(const float4*)&ldsW[k + kk][cbase];
#pragma unroll
            for (int r = 0; r < 4; r++) {
                float xs = xp[r * 4 + kk];
                acc[r][0] += xs * wv.x;
                acc[r][1] += xs * wv.y;
                acc[r][2] += xs * wv.z;
                acc[r][3] += xs * wv.w;
            }
        }
    }
#pragma unroll
    for (int r = 0; r < 4; r++) {
        int row = row0 + rbase + r;
        if (row < N) {
            float sc = SCALE ? dinv[row] : 1.0f;
            ushort4 o;
            o.x = f2bf(acc[r][0] * sc); o.y = f2bf(acc[r][1] * sc);
            o.z = f2bf(acc[r][2] * sc); o.w = f2bf(acc[r][3] * sc);
            *(ushort4*)&out[(size_t)row * M + col0 + cbase] = o;
        }
    }
}

// Final matmul: out[N,128] = Q[N,64]@Wd + r[row]*b1[col] + b2[col], fp32 out.
__global__ __launch_bounds__(256, 4) void matmul_out_kernel(
    const unsigned short* __restrict__ X, const float* __restrict__ W,
    const float* __restrict__ rvec, const float* __restrict__ b1,
    const float* __restrict__ b2, float* __restrict__ out, int N) {
    const int K = 64, M = 128;
    const int KP = K + 4;
    __shared__ float ldsW[K][64];
    __shared__ float ldsX[64][KP];
    int tid = threadIdx.x;
    int row0 = blockIdx.x * 64;
    int col0 = blockIdx.y * 64;

    for (int i = tid; i < K * 16; i += 256) {
        int k = i >> 4, j4 = i & 15;
        ((float4*)&ldsW[k][0])[j4] =
            *(const float4*)&W[(size_t)k * M + col0 + j4 * 4];
    }
    int maxr = N - row0; if (maxr > 64) maxr = 64;
    for (int i = tid; i < maxr * (K / 8); i += 256) {
        int r = i / (K / 8), c8 = i % (K / 8);
        uint4 u = *(const uint4*)&X[(size_t)(row0 + r) * K + c8 * 8];
        float* dp = &ldsX[r][c8 * 8];
        dp[0] = bf2f_lo(u.x); dp[1] = bf2f_hi(u.x);
        dp[2] = bf2f_lo(u.y); dp[3] = bf2f_hi(u.y);
        dp[4] = bf2f_lo(u.z); dp[5] = bf2f_hi(u.z);
        dp[6] = bf2f_lo(u.w); dp[7] = bf2f_hi(u.w);
    }
    __syncthreads();

    int cg = tid & 15, rg = tid >> 4;
    int rbase = rg * 4, cbase = cg * 4;
    float acc[4][4] = {};
#pragma unroll 2
    for (int k = 0; k < K; k += 4) {
        float4 xv[4];
#pragma unroll
        for (int r = 0; r < 4; r++)
            xv[r] = *(const float4*)&ldsX[rbase + r][k];
        const float* xp = (const float*)xv;
#pragma unroll
        for (int kk = 0; kk < 4; kk++) {
            float4 wv = *(const float4*)&ldsW[k + kk][cbase];
#pragma unroll
            for (int r = 0; r < 4; r++) {
                float xs = xp[r * 4 + kk];
                acc[r][0] += xs * wv.x;
                acc[r][1] += xs * wv.y;
                acc[r][2] += xs * wv.z;
                acc[r][3] += xs * wv.w;
            }
        }
    }
    float4 b1v = *(const float4*)&b1[col0 + cbase];
    float4 b2v = *(const float4*)&b2[col0 + cbase];
#pragma unroll
    for (int r = 0; r < 4; r++) {
        int row = row0 + rbase + r;
        if (row < N) {
            float rr = rvec[row];
            float4 o = make_float4(acc[r][0] + rr * b1v.x + b2v.x,
                                   acc[r][1] + rr * b1v.y + b2v.y,
                                   acc[r][2] + rr * b1v.z + b2v.z,
                                   acc[r][3] + rr * b1v.w + b2v.w);
            *(float4*)&out[(size_t)row * M + col0 + cbase] = o;
        }
    }
}

// 128-col aggregation, half-wave row-split (R10). Wave = 2 half-waves:
// parity p = lane>>5 handles edges e+2j+p; lane c = lane&31 owns cols
// {4c..4c+3} via one uint2 (8 B) load. 16 edges in flight per wave.
// Parities merged with __shfl_xor(...,32) at the end.
// WR: also emit r[d] = dinv[d]*sum(dinv[src]) (rank-1 bias, = A*ones).
template <bool PRE, bool WR>
__global__ __launch_bounds__(256) void agg_kernel(
    const unsigned short* __restrict__ Y, const int* __restrict__ offsets,
    const int* __restrict__ esrc, const float* __restrict__ dinv,
    unsigned short* __restrict__ out, float* __restrict__ rout, int N) {
    int wid = (blockIdx.x * blockDim.x + threadIdx.x) >> 6;
    int lane = threadIdx.x & 63;
    if (wid >= N) return;
    int beg = offsets[wid], end = offsets[wid + 1];
    int p = lane >> 5;
    int c = lane & 31;
    const uint2* Yu2 = (const uint2*)Y;   // row = 32 uint2 (256 B)
    float a0 = 0.f, a1 = 0.f, a2 = 0.f, a3 = 0.f, ad = 0.f;
    int e = beg;
    for (; e + 16 <= end; e += 16) {
        int ss[8];
#pragma unroll
        for (int j = 0; j < 8; j++) ss[j] = esrc[e + 2 * j + p];
        uint2 vv[8];
#pragma unroll
        for (int j = 0; j < 8; j++) vv[j] = Yu2[(size_t)ss[j] * 32 + c];
        if (WR) {
#pragma unroll
            for (int j = 0; j < 8; j++) ad += dinv[ss[j]];
        }
#pragma unroll
        for (int j = 0; j < 8; j++) {
            a0 += bf2f_lo(vv[j].x); a1 += bf2f_hi(vv[j].x);
            a2 += bf2f_lo(vv[j].y); a3 += bf2f_hi(vv[j].y);
        }
    }
    for (; e + 8 <= end; e += 8) {
        int ss[4];
#pragma unroll
        for (int j = 0; j < 4; j++) ss[j] = esrc[e + 2 * j + p];
        uint2 vv[4];
#pragma unroll
        for (int j = 0; j < 4; j++) vv[j] = Yu2[(size_t)ss[j] * 32 + c];
        if (WR) {
#pragma unroll
            for (int j = 0; j < 4; j++) ad += dinv[ss[j]];
        }
#pragma unroll
        for (int j = 0; j < 4; j++) {
            a0 += bf2f_lo(vv[j].x); a1 += bf2f_hi(vv[j].x);
            a2 += bf2f_lo(vv[j].y); a3 += bf2f_hi(vv[j].y);
        }
    }
    for (; e + 2 <= end; e += 2) {
        int s = esrc[e + p];
        uint2 v = Yu2[(size_t)s * 32 + c];
        if (WR) ad += dinv[s];
        a0 += bf2f_lo(v.x); a1 += bf2f_hi(v.x);
        a2 += bf2f_lo(v.y); a3 += bf2f_hi(v.y);
    }
    if (e < end && p == 0) {
        int s = esrc[e];
        uint2 v = Yu2[(size_t)s * 32 + c];
        if (WR) ad += dinv[s];
        a0 += bf2f_lo(v.x); a1 += bf2f_hi(v.x);
        a2 += bf2f_lo(v.y); a3 += bf2f_hi(v.y);
    }
    a0 += __shfl_xor(a0, 32);
    a1 += __shfl_xor(a1, 32);
    a2 += __shfl_xor(a2, 32);
    a3 += __shfl_xor(a3, 32);
    if (WR) ad += __shfl_xor(ad, 32);
    float dd = dinv[wid];
    float r0 = a0 * dd, r1 = a1 * dd, r2 = a2 * dd, r3 = a3 * dd;
    if (PRE) { r0 *= dd; r1 *= dd; r2 *= dd; r3 *= dd; }
    if (p == 0) {
        uint2 o;
        o.x = (unsigned)f2bf(r0) | ((unsigned)f2bf(r1) << 16);
        o.y = (unsigned)f2bf(r2) | ((unsigned)f2bf(r3) << 16);
        ((uint2*)out)[(size_t)wid * 32 + c] = o;
        if (WR && c == 0) rout[wid] = ad * dd;
    }
}

// Second encoder agg + fused VAE head epilogue, half-wave row-split.
// Input V = dinv*(A X Wc), Wc cols interleaved (even=mean, odd=lv).
// Lane c (half-wave 0) ends up with cols {4c..4c+3} = (mean,lv) pairs for
// output cols {2c, 2c+1}.  mean = T + r*bc + b2c; z = noise*exp(.5 lv)+mean;
// zb = dinv*z (bf16, prescaled for the decoder aggregation chain).
__global__ __launch_bounds__(256) void aggmeanlv_kernel(
    const unsigned short* __restrict__ Y, const int* __restrict__ offsets,
    const int* __restrict__ esrc, const float* __restrict__ dinv,
    const float* __restrict__ rvec, const float* __restrict__ bc,
    const float* __restrict__ b2c, const float* __restrict__ noise,
    float* __restrict__ mean, float* __restrict__ lv, float* __restrict__ z,
    unsigned short* __restrict__ zb, int N) {
    int wid = (blockIdx.x * blockDim.x + threadIdx.x) >> 6;
    int lane = threadIdx.x & 63;
    if (wid >= N) return;
    int beg = offsets[wid], end = offsets[wid + 1];
    int p = lane >> 5;
    int c = lane & 31;
    const uint2* Yu2 = (const uint2*)Y;
    float a0 = 0.f, a1 = 0.f, a2 = 0.f, a3 = 0.f;
    int e = beg;
    for (; e + 16 <= end; e += 16) {
        int ss[8];
#pragma unroll
        for (int j = 0; j < 8; j++) ss[j] = esrc[e + 2 * j + p];
        uint2 vv[8];
#pragma unroll
        for (int j = 0; j < 8; j++) vv[j] = Yu2[(size_t)ss[j] * 32 + c];
#pragma unroll
        for (int j = 0; j < 8; j++) {
            a0 += bf2f_lo(vv[j].x); a1 += bf2f_hi(vv[j].x);
            a2 += bf2f_lo(vv[j].y); a3 += bf2f_hi(vv[j].y);
        }
    }
    for (; e + 8 <= end; e += 8) {
        int ss[4];
#pragma unroll
        for (int j = 0; j < 4; j++) ss[j] = esrc[e + 2 * j + p];
        uint2 vv[4];
#pragma unroll
        for (int j = 0; j < 4; j++) vv[j] = Yu2[(size_t)ss[j] * 32 + c];
#pragma unroll
        for (int j = 0; j < 4; j++) {
            a0 += bf2f_lo(vv[j].x); a1 += bf2f_hi(vv[j].x);
            a2 += bf2f_lo(vv[j].y); a3 += bf2f_hi(vv[j].y);
        }
    }
    for (; e + 2 <= end; e += 2) {
        int s = esrc[e + p];
        uint2 v = Yu2[(size_t)s * 32 + c];
        a0 += bf2f_lo(v.x); a1 += bf2f_hi(v.x);
        a2 += bf2f_lo(v.y); a3 += bf2f_hi(v.y);
    }
    if (e < end && p == 0) {
        int s = esrc[e];
        uint2 v = Yu2[(size_t)s * 32 + c];
        a0 += bf2f_lo(v.x); a1 += bf2f_hi(v.x);
        a2 += bf2f_lo(v.y); a3 += bf2f_hi(v.y);
    }
    a0 += __shfl_xor(a0, 32);
    a1 += __shfl_xor(a1, 32);
    a2 += __shfl_xor(a2, 32);
    a3 += __shfl_xor(a3, 32);
    if (p == 0) {
        float dd = dinv[wid];
        float rr = rvec[wid];
        float4 bcv = ((const float4*)bc)[c];
        float4 b2v = ((const float4*)b2c)[c];
        float m0 = a0 * dd + rr * bcv.x + b2v.x;
        float l0 = a1 * dd + rr * bcv.y + b2v.y;
        float m1 = a2 * dd + rr * bcv.z + b2v.z;
        float l1 = a3 * dd + rr * bcv.w + b2v.w;
        float2 nv = ((const float2*)noise)[(size_t)wid * 32 + c];
        float z0 = nv.x * expf(0.5f * l0) + m0;
        float z1 = nv.y * expf(0.5f * l1) + m1;
        ((float2*)mean)[(size_t)wid * 32 + c] = make_float2(m0, m1);
        ((float2*)lv)[(size_t)wid * 32 + c] = make_float2(l0, l1);
        ((float2*)z)[(size_t)wid * 32 + c] = make_float2(z0, z1);
        unsigned zq = (unsigned)f2bf(z0 * dd) |
                      ((unsigned)f2bf(z1 * dd) << 16);
        ((unsigned*)zb)[(size_t)wid * 32 + c] = zq;
    }
}

// 64-col aggregation (decoder, z-space), quarter-wave row-split: parity
// p = lane>>4 (0..3) handles edges e+4j+p; lane c = lane&15 owns cols
// {4c..4c+3} via one uint2 load (one load instruction = 4 rows = 512 B).
template <bool PRE>
__global__ __launch_bounds__(256) void agg64_kernel(
    const unsigned short* __restrict__ Y, const int* __restrict__ offsets,
    const int* __restrict__ esrc, const float* __restrict__ dinv,
    unsigned short* __restrict__ out, int N) {
    int wid = (blockIdx.x * blockDim.x + threadIdx.x) >> 6;
    int lane = threadIdx.x & 63;
    if (wid >= N) return;
    int beg = offsets[wid], end = offsets[wid + 1];
    int p = lane >> 4;
    int c = lane & 15;
    const uint2* Yu2 = (const uint2*)Y;   // row = 16 uint2 (128 B)
    float a0 = 0.f, a1 = 0.f, a2 = 0.f, a3 = 0.f;
    int e = beg;
    for (; e + 16 <= end; e += 16) {
        int ss[4];
#pragma unroll
        for (int j = 0; j < 4; j++) ss[j] = esrc[e + 4 * j + p];
        uint2 vv[4];
#pragma unroll
        for (int j = 0; j < 4; j++) vv[j] = Yu2[(size_t)ss[j] * 16 + c];
#pragma unroll
        for (int j = 0; j < 4; j++) {
            a0 += bf2f_lo(vv[j].x); a1 += bf2f_hi(vv[j].x);
            a2 += bf2f_lo(vv[j].y); a3 += bf2f_hi(vv[j].y);
        }
    }
    for (; e + 4 <= end; e += 4) {
        int s = esrc[e + p];
        uint2 v = Yu2[(size_t)s * 16 + c];
        a0 += bf2f_lo(v.x); a1 += bf2f_hi(v.x);
        a2 += bf2f_lo(v.y); a3 += bf2f_hi(v.y);
    }
    int rem = end - e;
    if (p < rem) {
        int s = esrc[e + p];
        uint2 v = Yu2[(size_t)s * 16 + c];
        a0 += bf2f_lo(v.x); a1 += bf2f_hi(v.x);
        a2 += bf2f_lo(v.y); a3 += bf2f_hi(v.y);
    }
    a0 += __shfl_xor(a0, 16);
    a1 += __shfl_xor(a1, 16);
    a2 += __shfl_xor(a2, 16);
    a3 += __shfl_xor(a3, 16);
    a0 += __shfl_xor(a0, 32);
    a1 += __shfl_xor(a1, 32);
    a2 += __shfl_xor(a2, 32);
    a3 += __shfl_xor(a3, 32);
    if (lane < 16) {
        float dd = dinv[wid];
        float r0 = a0 * dd, r1 = a1 * dd, r2 = a2 * dd, r3 = a3 * dd;
        if (PRE) { r0 *= dd; r1 *= dd; r2 *= dd; r3 *= dd; }
        uint2 o;
        o.x = (unsigned)f2bf(r0) | ((unsigned)f2bf(r1) << 16);
        o.y = (unsigned)f2bf(r2) | ((unsigned)f2bf(r3) << 16);
        ((uint2*)out)[(size_t)wid * 16 + c] = o;
    }
}

extern "C" void kernel_launch(void* const* d_in, const int* in_sizes, int n_in,
                              void* d_out, int out_size, void* d_ws,
                              size_t ws_size, hipStream_t stream) {
    const float* feature = (const float*)d_in[0];
    const int*   ei      = (const int*)d_in[1];
    const float* noise   = (const float*)d_in[2];
    const float* W_enc   = (const float*)d_in[3];
    const float* b_enc   = (const float*)d_in[4];
    const float* W_mean  = (const float*)d_in[5];
    const float* b_mean  = (const float*)d_in[6];
    const float* W_lv    = (const float*)d_in[7];
    const float* b_lv    = (const float*)d_in[8];
    const float* W_d1    = (const float*)d_in[9];
    const float* b_d1    = (const float*)d_in[10];
    const float* W_d2    = (const float*)d_in[11];
    const float* b_d2    = (const float*)d_in[12];

    int N = in_sizes[0] / 128;
    int E = in_sizes[1] / 2;
    int nb = (N + 255) >> 8;

    float* z_out    = (float*)d_out;
    float* mean_out = z_out + (size_t)N * 64;
    float* lv_out   = z_out + (size_t)N * 128;
    float* gout     = z_out + (size_t)N * 192;

    char* ws = (char*)d_ws;
    unsigned short* Ybf = (unsigned short*)ws; ws += (size_t)N * 128 * 2;
    unsigned short* Hbf = (unsigned short*)ws; ws += (size_t)N * 128 * 2;
    unsigned short* Zbf = (unsigned short*)ws; ws += (size_t)N * 64 * 2;
    int*   esrc  = (int*)ws;   ws += (size_t)(E + N) * 4;
    int*   offs  = (int*)ws;   ws += (size_t)(N + 1) * 4;
    float* dinv  = (float*)ws; ws += (size_t)N * 4;
    int*   gcnt  = (int*)ws;   ws += 256 * 8 * 4;
    int*   bbase = (int*)ws;   ws += 256 * 4;
    float* rvec  = (float*)ws; ws += (size_t)N * 4;
    float* Wc    = (float*)ws; ws += 128 * 128 * 4;
    float* Wd    = (float*)ws; ws += 64 * 128 * 4;
    float* bc    = (float*)ws; ws += 128 * 4;
    float* b2c   = (float*)ws; ws += 128 * 4;
    float* bd12  = (float*)ws; ws += 128 * 4;

    // `pairs` ALIASES Ybf+Hbf (CSR build completes before matmuls touch Ybf).
    uint2* pairs = (uint2*)Ybf;
    size_t pairRegion = (size_t)N * 128 * 2 * 2;
    int capS = 1536;
    int capMax = (int)(pairRegion / (256 * 8 * sizeof(uint2)));
    if (capS > capMax) capS = capMax;

    const int* src = ei;
    const int* dst = ei + E;
    int total = E + N;

    // ---- CSR build (coalesced counting sort) ----
    zero_kernel<<<(256 * 8 + 255) / 256, 256, 0, stream>>>(gcnt, 256 * 8);
    bucketize_kernel<<<(total + 4095) / 4096, 256, 0, stream>>>(
        src, dst, E, N, capS, pairs, gcnt);
    scan_bases_kernel<<<1, 256, 0, stream>>>(gcnt, nb, capS, bbase, offs, N);
    build_kernel<<<nb, 256, 0, stream>>>(pairs, gcnt, capS, bbase, N, offs,
                                         dinv, esrc);

    // ---- collapsed weights (tiny) ----
    wcomb_kernel<<<(16384 + 8192 + 384 + 255) / 256, 256, 0, stream>>>(
        W_enc, b_enc, W_mean, b_mean, W_lv, b_lv, W_d1, b_d1, W_d2,
        Wc, bc, b2c, Wd, bd12);

    int gx = (N + 63) / 64;
    int aggBlocks = (int)(((size_t)N * 64 + 255) / 256);

    // ---- encoder: meanlv = A^2 X Wc + r*bc + b2c ----
    matmul_kernel<128, false, true><<<dim3(gx, 2), 256, 0, stream>>>(
        feature, Wc, dinv, Ybf, N);                      // U = dinv*(X@Wc)
    agg_kernel<true, true><<<aggBlocks, 256, 0, stream>>>(
        Ybf, offs, esrc, dinv, Hbf, rvec, N);            // V = dinv*(A X Wc), r
    aggmeanlv_kernel<<<aggBlocks, 256, 0, stream>>>(
        Hbf, offs, esrc, dinv, rvec, bc, b2c, noise,
        mean_out, lv_out, z_out, Zbf, N);                // mean/lv/z + zb

    // ---- decoder: out = A^2 z Wd + r*bd12 + bd2 ----
    agg64_kernel<true><<<aggBlocks, 256, 0, stream>>>(
        Zbf, offs, esrc, dinv, Ybf, N);                  // P = dinv*(A z)
    agg64_kernel<false><<<aggBlocks, 256, 0, stream>>>(
        Ybf, offs, esrc, dinv, Hbf, N);                  // Q = A^2 z
    matmul_out_kernel<<<dim3(gx, 2), 256, 0, stream>>>(
        Hbf, Wd, rvec, bd12, b_d2, gout, N);             // out (fp32)
}